// Round 12
// baseline (2961.283 us; speedup 1.0000x reference)
//
#include <hip/hip_runtime.h>
#include <cstdint>
#include <cstddef>

// Bidirectional LSTM  B=32 T=1024 D=512 H=256 (torch gate order i,f,g,o), fp32 in/out.
//
// Phase 1: xp = x @ Wih^T + bias  (fp16 MFMA GEMM, xp fp16)
// Phase 2: BATCH-PACKED all-to-all MFMA recurrence. True per-step work is
//   gates[1024][32] = Whh @ h[256][32] per dir (batches share Whh) -> pack 16
//   batches into the 16 MFMA B-columns (kills the 16x col-redundancy of R5-R11).
//   64 active blocks = (dir x bgroup x mslice16); group of 16 blocks placed on one
//   XCD via bid%8 (grid 128, others exit; perf heuristic only). Block: 256 thr
//   (4 waves = 4 gates), owns 16 outputs x 16 batches; 8 weight frags/wave in VGPRs.
//   h in 16KB parity-double-buffered XOR-swizzled LDS. Exchange: parity-versioned
//   8B entries {2 fp16, ver} (R11 protocol), 15 peers x 128 entries, probed at
//   previous-step tail. 2 lgkm-only barriers/step.

typedef unsigned int   uint;
typedef unsigned short ushort;
typedef unsigned long long ull;

constexpr int Tn = 1024;
constexpr int Bn = 32;
constexpr int Dn = 512;
constexpr int Hn = 256;
constexpr int NC = 2048;          // 2 dirs * 4H
constexpr int KT = 512;           // K of the input projection

typedef _Float16 half8  __attribute__((ext_vector_type(8)));
typedef float    f32x4  __attribute__((ext_vector_type(4)));

__device__ __forceinline__ ushort f2h(float f) {
  _Float16 h = (_Float16)f;               // RNE
  return __builtin_bit_cast(ushort, h);
}
__device__ __forceinline__ float h2f(ushort s) {
  return (float)__builtin_bit_cast(_Float16, s);
}
__device__ __forceinline__ uint packh(float a, float b) {
  return (uint)f2h(a) | ((uint)f2h(b) << 16);
}
__device__ __forceinline__ f32x4 mf(uint4 a, uint4 b, f32x4 c) {
  return __builtin_amdgcn_mfma_f32_16x16x32_f16(
      __builtin_bit_cast(half8, a), __builtin_bit_cast(half8, b), c, 0, 0, 0);
}

__device__ __forceinline__ float sig_(float x) {
  x = fminf(fmaxf(x, -30.f), 30.f);
  return 1.f / (1.f + __expf(-x));
}
__device__ __forceinline__ float tanh_(float x) {
  x = fminf(fmaxf(x, -15.f), 15.f);
  float e = __expf(2.f * x);
  return (e - 1.f) / (e + 1.f);
}

// lgkm-only block barrier (no vmcnt drain: out/EX stores stay in flight)
__device__ __forceinline__ void barrier_lgkm() {
  asm volatile("s_waitcnt lgkmcnt(0)" ::: "memory");
  __builtin_amdgcn_s_barrier();
}

// ---------------- prep kernels ----------------

__global__ void k_prep_a(const float* __restrict__ x, ushort* __restrict__ a16, long nquad) {
  long i4 = (long)blockIdx.x * blockDim.x + threadIdx.x;
  if (i4 >= nquad) return;
  const float4 v = ((const float4*)x)[i4];
  ushort4 o;
  o.x = f2h(v.x); o.y = f2h(v.y); o.z = f2h(v.z); o.w = f2h(v.w);
  ((ushort4*)a16)[i4] = o;
}

__global__ void k_prep_w(const float* __restrict__ wf, const float* __restrict__ wb,
                         const float* __restrict__ bf1, const float* __restrict__ bf2,
                         const float* __restrict__ bb1, const float* __restrict__ bb2,
                         ushort* __restrict__ w16, float* __restrict__ biasc) {
  long i4 = (long)blockIdx.x * blockDim.x + threadIdx.x;
  if (i4 >= (long)NC * (KT / 4)) return;
  int n = (int)(i4 >> 7);
  int k4 = (int)(i4 & 127);
  int dir = n >> 10, g = n & 1023;
  const float* w = dir ? wb : wf;
  const float4 v = ((const float4*)(w + (size_t)g * Dn))[k4];
  ushort4 o;
  o.x = f2h(v.x); o.y = f2h(v.y); o.z = f2h(v.z); o.w = f2h(v.w);
  ((ushort4*)w16)[i4] = o;
  if (k4 == 0) biasc[n] = dir ? (bb1[g] + bb2[g]) : (bf1[g] + bf2[g]);
}

// Whh -> A-frags WF[dir][ms][g][kt][lane]: row = g*256 + ms*16 + (lane&15),
// k = kt*32 + (lane>>4)*8.  (bg groups reuse the same weights.)
__global__ void k_prep_whh(const float* __restrict__ whhF, const float* __restrict__ whhB,
                           uint4* __restrict__ WF) {
  int t = blockIdx.x * blockDim.x + threadIdx.x;   // 0 .. 65535
  if (t >= 2 * 16 * 4 * 8 * 64) return;
  int lane = t & 63;
  int rest = t >> 6;
  int kt = rest & 7;
  int g  = (rest >> 3) & 3;
  int ms = (rest >> 5) & 15;
  int dir = rest >> 9;
  int row = g * 256 + ms * 16 + (lane & 15);
  int kb  = kt * 32 + (lane >> 4) * 8;
  const float* whh = dir ? whhB : whhF;
  const float4* s = (const float4*)(whh + (size_t)row * Hn + kb);
  float4 v0 = s[0], v1 = s[1];
  WF[t] = (uint4){ packh(v0.x, v0.y), packh(v0.z, v0.w),
                   packh(v1.x, v1.y), packh(v1.z, v1.w) };
}

__global__ void k_bad(float* __restrict__ out, int n) {
  int i = blockIdx.x * blockDim.x + threadIdx.x;
  if (i < n) out[i] = 54321.f;
}

// ---------------- phase 1: fp16 MFMA GEMM (unchanged) ----------------

__device__ __forceinline__ void gload_lds16(const void* g, void* l) {
  __builtin_amdgcn_global_load_lds((const __attribute__((address_space(1))) void*)g,
                                   (__attribute__((address_space(3))) void*)l, 16, 0, 0);
}

__global__ __launch_bounds__(256) void k_gemm(const ushort* __restrict__ A,
                                              const ushort* __restrict__ W,
                                              const float* __restrict__ biasc,
                                              ushort* __restrict__ xp) {
  __shared__ __align__(16) ushort As[128 * 32];
  __shared__ __align__(16) ushort Bs[128 * 32];
  const int bid = blockIdx.x;
  const int m0 = (bid >> 4) * 128;
  const int n0 = (bid & 15) * 128;
  const int tid = threadIdx.x;
  const int wid = tid >> 6, lane = tid & 63;
  const int wr = wid >> 1, wcq = wid & 1;
  const int l16 = lane & 15, lq = lane >> 4;

  f32x4 acc[4][4] = {};

  for (int kt = 0; kt < KT; kt += 32) {
    __syncthreads();
#pragma unroll
    for (int i = 0; i < 2; ++i) {
      int ch = wid * 2 + i;
      int p = ch * 64 + lane;
      int r = p >> 2, gp = p & 3;
      int gs = gp ^ ((r >> 1) & 3);
      gload_lds16(A + (size_t)(m0 + r) * KT + kt + gs * 8, (char*)As + ch * 1024);
      gload_lds16(W + (size_t)(n0 + r) * KT + kt + gs * 8, (char*)Bs + ch * 1024);
    }
    __syncthreads();

    half8 af[4], bfr[4];
#pragma unroll
    for (int mfi = 0; mfi < 4; ++mfi) {
      int row = wr * 64 + mfi * 16 + l16;
      int g = lq ^ ((row >> 1) & 3);
      af[mfi] = *(const half8*)((const char*)As + row * 64 + g * 16);
    }
#pragma unroll
    for (int nf = 0; nf < 4; ++nf) {
      int row = wcq * 64 + nf * 16 + l16;
      int g = lq ^ ((row >> 1) & 3);
      bfr[nf] = *(const half8*)((const char*)Bs + row * 64 + g * 16);
    }
#pragma unroll
    for (int mfi = 0; mfi < 4; ++mfi)
#pragma unroll
      for (int nf = 0; nf < 4; ++nf)
        acc[mfi][nf] = __builtin_amdgcn_mfma_f32_16x16x32_f16(af[mfi], bfr[nf], acc[mfi][nf], 0, 0, 0);
  }

#pragma unroll
  for (int nf = 0; nf < 4; ++nf) {
    int col = n0 + wcq * 64 + nf * 16 + l16;
    float bv = biasc[col];
#pragma unroll
    for (int mfi = 0; mfi < 4; ++mfi) {
      int rbase = m0 + wr * 64 + mfi * 16 + lq * 4;
#pragma unroll
      for (int i = 0; i < 4; ++i)
        xp[(size_t)(rbase + i) * NC + col] = f2h(acc[mfi][nf][i] + bv);
    }
  }
}

// ---------------- phase 2: batch-packed all-to-all recurrence ----------------
// grid 128; xg = bid&7 (intended XCD), active if xg < 2*nbg; ms = bid>>3.
// dir = xg/nbg, bg = xg%nbg. pub = xg*16+ms. EX[slot][pub][128]: entry j =
// (opair<<4)|b = {h[o], h[o+1] fp16, version}. Step t consumes ver t (probed at
// prev tail), posts ver t+1 to slot (t+1)&1. hb rows XOR-swizzled by ((b&7)<<4).

__global__ __launch_bounds__(256, 2) void k_lstm(const uint4* __restrict__ WF,
                                                 const ushort* __restrict__ xp,
                                                 float* __restrict__ out,
                                                 ull* __restrict__ EX,
                                                 int b_base, int nbg) {
  const int xg = blockIdx.x & 7;
  if (xg >= 2 * nbg) return;
  const int ms  = blockIdx.x >> 3;
  const int dir = xg / nbg;
  const int bg  = xg % nbg;
  const int pub = xg * 16 + ms;
  const int tid = threadIdx.x;
  const int w    = tid >> 6;       // wave = gate
  const int lane = tid & 63;
  const int bcol = lane & 15;      // MFMA B col = batch
  const int kc   = lane >> 4;
  const int o    = tid & 15;       // tail: output-local
  const int b    = tid >> 4;       // tail: batch-local

  __shared__ __align__(16) char  hb[2][8192];   // [parity][b][512B swizzled row]
  __shared__ __align__(16) float gbuf[1024];    // [g][b][o] (+XOR swz)

  // ---- weights: 8 frags (32 VGPRs) ----
  uint4 w8[8];
  {
    const uint4* base = WF + (size_t)(((dir * 16 + ms) * 4 + w) * 8) * 64 + lane;
#pragma unroll
    for (int kt = 0; kt < 8; ++kt) w8[kt] = base[(size_t)kt * 64];
  }

  // ---- exchange decode tables (15 peers x 128 entries = 1920, 8/thread) ----
  uint exoff[8], ldsoff[8];
#pragma unroll
  for (int i = 0; i < 8; ++i) {
    int e = tid + 256 * i;
    if (e < 1920) {
      int pm15 = e >> 7, j = e & 127;
      int pm = pm15 + (pm15 >= ms ? 1 : 0);
      int be = j & 15, op = j >> 4;
      int og = pm * 16 + 2 * op;
      exoff[i]  = (uint)((xg * 16 + pm) * 128 + j);
      ldsoff[i] = (uint)(be * 512 + ((2 * og) ^ ((be & 7) << 4)));
    } else exoff[i] = 0xffffffffu;
  }
  ull pv[8];
#pragma unroll
  for (int i = 0; i < 8; ++i) pv[i] = 0xffffffff00000000ull;

#pragma unroll
  for (int i = 0; i < 16; ++i) ((uint*)hb)[tid + 256 * i] = 0;   // h_{-1} = 0
  float creg = 0.f;
  __syncthreads();

  const int dstep = dir ? -1 : 1;
  const int t0 = dir ? (Tn - 1) : 0;
  const ptrdiff_t xstr = (ptrdiff_t)dstep * NC;
  const ptrdiff_t ostr = (ptrdiff_t)dstep * 512;
  const ushort* px = xp + ((size_t)(bg * 16 + b) * Tn + t0) * NC + dir * 1024 + ms * 16 + o;
  float* pout = out + ((size_t)(b_base + bg * 16 + b) * Tn + t0) * 512 + dir * 256 + ms * 16 + o;
  const uint own_lds = (uint)(b * 512 + ((2 * (ms * 16 + o)) ^ ((b & 7) << 4)));
  const size_t ex_post = (size_t)pub * 128 + (size_t)(((o >> 1) << 4) | b);

  int cur = 0;
#pragma unroll 1
  for (int t = 0; t < Tn; ++t) {
    // xp loads early (used in tail)
    ushort xq0 = px[0], xq1 = px[256], xq2 = px[512], xq3 = px[768];
    px += xstr;

    // resolve probes (re-poll stale), write peer h into hb[cur]
    const ull* exs = EX + (size_t)(t & 1) * 8192;
#pragma unroll
    for (int i = 0; i < 8; ++i) {
      if (exoff[i] != 0xffffffffu) {
        ull v = pv[i];
        while ((uint)(v >> 32) != (uint)t)
          v = __hip_atomic_load(exs + exoff[i], __ATOMIC_RELAXED, __HIP_MEMORY_SCOPE_AGENT);
        *(uint*)(hb[cur] + ldsoff[i]) = (uint)v;
      }
    }
    barrier_lgkm();                 // B1: full h_{t-1} in hb[cur]

    // B-frags (cols = 16 batches) + MFMA (2 chains)
    uint4 bf[8];
    const char* hc = hb[cur];
#pragma unroll
    for (int kt = 0; kt < 8; ++kt)
      bf[kt] = *(const uint4*)(hc + bcol * 512 + ((kt * 64 + kc * 16) ^ ((bcol & 7) << 4)));
    f32x4 aE = {0.f, 0.f, 0.f, 0.f}, aO = {0.f, 0.f, 0.f, 0.f};
#pragma unroll
    for (int k4 = 0; k4 < 4; ++k4) {
      aE = mf(w8[2 * k4],     bf[2 * k4],     aE);
      aO = mf(w8[2 * k4 + 1], bf[2 * k4 + 1], aO);
    }
    f32x4 acc = aE + aO;
    *(f32x4*)&gbuf[(w * 256 + bcol * 16 + kc * 4) ^ ((bcol & 3) << 2)] = acc;
    barrier_lgkm();                 // B2: all gates in gbuf

    // tail: thread owns (o, b)
    float gi = gbuf[(0 * 256 + b * 16 + o) ^ ((b & 3) << 2)] + h2f(xq0);
    float gf = gbuf[(1 * 256 + b * 16 + o) ^ ((b & 3) << 2)] + h2f(xq1);
    float gg = gbuf[(2 * 256 + b * 16 + o) ^ ((b & 3) << 2)] + h2f(xq2);
    float go = gbuf[(3 * 256 + b * 16 + o) ^ ((b & 3) << 2)] + h2f(xq3);
    float iv = sig_(gi), fv = sig_(gf), gv = tanh_(gg), ov = sig_(go);
    creg = fv * creg + iv * gv;
    float h = ov * tanh_(creg);
    *pout = h;
    pout += ostr;
    float hn = __shfl_down(h, 1);   // lane+1 holds o+1, same b
    if (!(o & 1)) {
      uint p32 = packh(h, hn);
      *(uint*)(hb[cur ^ 1] + own_lds) = p32;                    // own h for next step
      __hip_atomic_store(EX + (size_t)((t + 1) & 1) * 8192 + ex_post,
                         (ull)p32 | ((ull)(uint)(t + 1) << 32),
                         __ATOMIC_RELAXED, __HIP_MEMORY_SCOPE_AGENT);
    }
    // probe next step's entries (latency hides under peers' skew + next poll)
    const ull* exn = EX + (size_t)((t + 1) & 1) * 8192;
#pragma unroll
    for (int i = 0; i < 8; ++i)
      if (exoff[i] != 0xffffffffu)
        pv[i] = __hip_atomic_load(exn + exoff[i], __ATOMIC_RELAXED, __HIP_MEMORY_SCOPE_AGENT);
    cur ^= 1;
  }
}

// ---------------- host ----------------

extern "C" void kernel_launch(void* const* d_in, const int* in_sizes, int n_in,
                              void* d_out, int out_size, void* d_ws, size_t ws_size,
                              hipStream_t stream) {
  const float* x     = (const float*)d_in[0];
  const float* Wih_f = (const float*)d_in[1];
  const float* Whh_f = (const float*)d_in[2];
  const float* bih_f = (const float*)d_in[3];
  const float* bhh_f = (const float*)d_in[4];
  const float* Wih_b = (const float*)d_in[5];
  const float* Whh_b = (const float*)d_in[6];
  const float* bib_b = (const float*)d_in[7];
  const float* bhh_b = (const float*)d_in[8];
  float* out = (float*)d_out;

  const size_t szW16  = (size_t)NC * KT * 2;            // 2 MiB
  const size_t szBias = (size_t)NC * 4;
  const size_t szWF   = (size_t)65536 * 16;             // 1 MiB frag buffer
  const size_t szEX   = (size_t)2 * 64 * 128 * 8;       // 128 KiB exchange

  int c = 0;
  size_t szA16 = 0, szXp = 0;
  for (int cc = 1; cc <= 2; cc *= 2) {                  // sizeB must be >= 16
    size_t a = (size_t)(Bn / cc) * Tn * KT * 2;
    size_t p = (size_t)(Bn / cc) * Tn * NC * 2;
    if (szW16 + szBias + szWF + szEX + a + p <= ws_size) { c = cc; szA16 = a; szXp = p; break; }
  }
  if (c == 0) {
    k_bad<<<(out_size + 255) / 256, 256, 0, stream>>>(out, out_size);
    return;
  }

  char* ws = (char*)d_ws;
  ushort* W16   = (ushort*)ws;
  float*  biasc = (float*)(ws + szW16);
  uint4*  WF    = (uint4*)(ws + szW16 + szBias);
  ull*    EX    = (ull*)(ws + szW16 + szBias + szWF);
  ushort* A16   = (ushort*)(ws + szW16 + szBias + szWF + szEX);
  ushort* xp    = (ushort*)(ws + szW16 + szBias + szWF + szEX + szA16);

  {
    long n4 = (long)NC * (KT / 4);
    k_prep_w<<<(int)((n4 + 255) / 256), 256, 0, stream>>>(Wih_f, Wih_b, bih_f, bhh_f,
                                                          bib_b, bhh_b, W16, biasc);
  }
  k_prep_whh<<<65536 / 256, 256, 0, stream>>>(Whh_f, Whh_b, WF);

  const int sizeB = Bn / c;          // 32 or 16
  const int nbg = sizeB / 16;        // 2 or 1
  for (int cb = 0; cb < c; ++cb) {
    const int b_base = cb * sizeB;
    {
      long nquad = (long)sizeB * Tn * KT / 4;
      k_prep_a<<<(int)((nquad + 255) / 256), 256, 0, stream>>>(
          x + (size_t)b_base * Tn * Dn, A16, nquad);
    }
    k_gemm<<<dim3(sizeB * 8 * 16), dim3(256), 0, stream>>>(A16, W16, biasc, xp);
    hipMemsetAsync(EX, 0, szEX, stream);
    k_lstm<<<dim3(128), dim3(256), 0, stream>>>(WF, xp, out, EX, b_base, nbg);
  }
}

// Round 13
// 2911.454 us; speedup vs baseline: 1.0171x; 1.0171x over previous
//
#include <hip/hip_runtime.h>
#include <cstdint>
#include <cstddef>

// Bidirectional LSTM  B=32 T=1024 D=512 H=256 (torch gate order i,f,g,o), fp32 in/out.
//
// Phase 1: xp = x @ Wih^T + bias  (fp16 MFMA GEMM, xp fp16)
// Phase 2: batch-packed MFMA recurrence, S=4 M-split. 16 active blocks =
//   4 groups (dir x bg) x 4 M-quarters; group xg pinned to XCD xg (grid 32,
//   xg=bid&7, q=bid>>3) -> peers share an XCD L2 (perf heuristic only).
//   Block: 256 thr = 4 waves; wave j owns tiles {(g,j): g=0..3} -> D frags hold
//   all 4 gates for the same (output,batch) IN-LANE -> activation in registers,
//   no gate bounce, 1 barrier/step. 32 weight frags = 128 VGPRs (budget 512).
//   Exchange: 8B entries {2xfp16, ver}, parity slots; 6 polls/thread resolved by a
//   PARALLEL re-poll loop (all stale entries reloaded per iteration); probed at
//   previous tail; 2 posts/thread paired in-lane. h in 16KB swizzled LDS.

typedef unsigned int   uint;
typedef unsigned short ushort;
typedef unsigned long long ull;

constexpr int Tn = 1024;
constexpr int Bn = 32;
constexpr int Dn = 512;
constexpr int Hn = 256;
constexpr int NC = 2048;          // 2 dirs * 4H
constexpr int KT = 512;           // K of the input projection
constexpr int NBex = 16 * 512;    // EX entries per parity slot

typedef _Float16 half8  __attribute__((ext_vector_type(8)));
typedef float    f32x4  __attribute__((ext_vector_type(4)));

__device__ __forceinline__ ushort f2h(float f) {
  _Float16 h = (_Float16)f;               // RNE
  return __builtin_bit_cast(ushort, h);
}
__device__ __forceinline__ float h2f(ushort s) {
  return (float)__builtin_bit_cast(_Float16, s);
}
__device__ __forceinline__ uint packh(float a, float b) {
  return (uint)f2h(a) | ((uint)f2h(b) << 16);
}
__device__ __forceinline__ f32x4 mf(uint4 a, uint4 b, f32x4 c) {
  return __builtin_amdgcn_mfma_f32_16x16x32_f16(
      __builtin_bit_cast(half8, a), __builtin_bit_cast(half8, b), c, 0, 0, 0);
}

__device__ __forceinline__ float sig_(float x) {
  x = fminf(fmaxf(x, -30.f), 30.f);
  return 1.f / (1.f + __expf(-x));
}
__device__ __forceinline__ float tanh_(float x) {
  x = fminf(fmaxf(x, -15.f), 15.f);
  float e = __expf(2.f * x);
  return (e - 1.f) / (e + 1.f);
}

__device__ __forceinline__ void barrier_lgkm() {
  asm volatile("s_waitcnt lgkmcnt(0)" ::: "memory");
  __builtin_amdgcn_s_barrier();
}

__device__ __forceinline__ ull exload(const ull* p) {
  return __hip_atomic_load(p, __ATOMIC_RELAXED, __HIP_MEMORY_SCOPE_AGENT);
}

// ---------------- prep kernels ----------------

__global__ void k_prep_a(const float* __restrict__ x, ushort* __restrict__ a16, long nquad) {
  long i4 = (long)blockIdx.x * blockDim.x + threadIdx.x;
  if (i4 >= nquad) return;
  const float4 v = ((const float4*)x)[i4];
  ushort4 o;
  o.x = f2h(v.x); o.y = f2h(v.y); o.z = f2h(v.z); o.w = f2h(v.w);
  ((ushort4*)a16)[i4] = o;
}

__global__ void k_prep_w(const float* __restrict__ wf, const float* __restrict__ wb,
                         const float* __restrict__ bf1, const float* __restrict__ bf2,
                         const float* __restrict__ bb1, const float* __restrict__ bb2,
                         ushort* __restrict__ w16, float* __restrict__ biasc) {
  long i4 = (long)blockIdx.x * blockDim.x + threadIdx.x;
  if (i4 >= (long)NC * (KT / 4)) return;
  int n = (int)(i4 >> 7);
  int k4 = (int)(i4 & 127);
  int dir = n >> 10, g = n & 1023;
  const float* w = dir ? wb : wf;
  const float4 v = ((const float4*)(w + (size_t)g * Dn))[k4];
  ushort4 o;
  o.x = f2h(v.x); o.y = f2h(v.y); o.z = f2h(v.z); o.w = f2h(v.w);
  ((ushort4*)w16)[i4] = o;
  if (k4 == 0) biasc[n] = dir ? (bb1[g] + bb2[g]) : (bf1[g] + bf2[g]);
}

// Whh -> A-frags. frag f = (dir*4+q)*128 + j*32 + g*8 + kt;
// row = g*256 + q*64 + j*16 + (lane&15); k = kt*32 + (lane>>4)*8.
__global__ void k_prep_whh(const float* __restrict__ whhF, const float* __restrict__ whhB,
                           uint4* __restrict__ WF) {
  int t = blockIdx.x * blockDim.x + threadIdx.x;   // 0 .. 65535
  if (t >= 1024 * 64) return;
  int lane = t & 63;
  int f = t >> 6;
  int kt = f & 7;
  int g  = (f >> 3) & 3;
  int j  = (f >> 5) & 3;
  int q  = (f >> 7) & 3;
  int dir = (f >> 9) & 1;
  int row = g * 256 + q * 64 + j * 16 + (lane & 15);
  int kb  = kt * 32 + (lane >> 4) * 8;
  const float* whh = dir ? whhB : whhF;
  const float4* s = (const float4*)(whh + (size_t)row * Hn + kb);
  float4 v0 = s[0], v1 = s[1];
  WF[t] = (uint4){ packh(v0.x, v0.y), packh(v0.z, v0.w),
                   packh(v1.x, v1.y), packh(v1.z, v1.w) };
}

__global__ void k_bad(float* __restrict__ out, int n) {
  int i = blockIdx.x * blockDim.x + threadIdx.x;
  if (i < n) out[i] = 54321.f;
}

// ---------------- phase 1: fp16 MFMA GEMM (unchanged) ----------------

__device__ __forceinline__ void gload_lds16(const void* g, void* l) {
  __builtin_amdgcn_global_load_lds((const __attribute__((address_space(1))) void*)g,
                                   (__attribute__((address_space(3))) void*)l, 16, 0, 0);
}

__global__ __launch_bounds__(256) void k_gemm(const ushort* __restrict__ A,
                                              const ushort* __restrict__ W,
                                              const float* __restrict__ biasc,
                                              ushort* __restrict__ xp) {
  __shared__ __align__(16) ushort As[128 * 32];
  __shared__ __align__(16) ushort Bs[128 * 32];
  const int bid = blockIdx.x;
  const int m0 = (bid >> 4) * 128;
  const int n0 = (bid & 15) * 128;
  const int tid = threadIdx.x;
  const int wid = tid >> 6, lane = tid & 63;
  const int wr = wid >> 1, wcq = wid & 1;
  const int l16 = lane & 15, lq = lane >> 4;

  f32x4 acc[4][4] = {};

  for (int kt = 0; kt < KT; kt += 32) {
    __syncthreads();
#pragma unroll
    for (int i = 0; i < 2; ++i) {
      int ch = wid * 2 + i;
      int p = ch * 64 + lane;
      int r = p >> 2, gp = p & 3;
      int gs = gp ^ ((r >> 1) & 3);
      gload_lds16(A + (size_t)(m0 + r) * KT + kt + gs * 8, (char*)As + ch * 1024);
      gload_lds16(W + (size_t)(n0 + r) * KT + kt + gs * 8, (char*)Bs + ch * 1024);
    }
    __syncthreads();

    half8 af[4], bfr[4];
#pragma unroll
    for (int mfi = 0; mfi < 4; ++mfi) {
      int row = wr * 64 + mfi * 16 + l16;
      int g = lq ^ ((row >> 1) & 3);
      af[mfi] = *(const half8*)((const char*)As + row * 64 + g * 16);
    }
#pragma unroll
    for (int nf = 0; nf < 4; ++nf) {
      int row = wcq * 64 + nf * 16 + l16;
      int g = lq ^ ((row >> 1) & 3);
      bfr[nf] = *(const half8*)((const char*)Bs + row * 64 + g * 16);
    }
#pragma unroll
    for (int mfi = 0; mfi < 4; ++mfi)
#pragma unroll
      for (int nf = 0; nf < 4; ++nf)
        acc[mfi][nf] = __builtin_amdgcn_mfma_f32_16x16x32_f16(af[mfi], bfr[nf], acc[mfi][nf], 0, 0, 0);
  }

#pragma unroll
  for (int nf = 0; nf < 4; ++nf) {
    int col = n0 + wcq * 64 + nf * 16 + l16;
    float bv = biasc[col];
#pragma unroll
    for (int mfi = 0; mfi < 4; ++mfi) {
      int rbase = m0 + wr * 64 + mfi * 16 + lq * 4;
#pragma unroll
      for (int i = 0; i < 4; ++i)
        xp[(size_t)(rbase + i) * NC + col] = f2h(acc[mfi][nf][i] + bv);
    }
  }
}

// ---------------- phase 2: S=4 batch-packed recurrence ----------------
// Block (xg = dir*nbg+bg, q): outputs [q*64,(q+1)*64) x 16 batches, all 4 gates.
// Wave j: tiles (g=0..3, j); lane (bcol=batch, kc): outputs q*64+j*16+kc*4..+3.
// EX[slot][pub=xg*4+q][512]: entry (opair<<4)|b = {h(2*opair),h(2*opair+1), ver}.
// Step t consumes ver t from slot t&1; posts ver t+1 to slot (t+1)&1.

__global__ __launch_bounds__(256, 1) void k_lstm(const uint4* __restrict__ WF,
                                                 const ushort* __restrict__ xp,
                                                 float* __restrict__ out,
                                                 ull* __restrict__ EX,
                                                 int b_base, int nbg) {
  const int xg = blockIdx.x & 7;
  if (xg >= 2 * nbg) return;
  const int q   = blockIdx.x >> 3;
  const int dir = xg / nbg;
  const int bg  = xg % nbg;
  const int pub = xg * 4 + q;
  const int tid = threadIdx.x;
  const int j    = tid >> 6;          // wave
  const int lane = tid & 63;
  const int bcol = lane & 15;         // batch (MFMA col)
  const int kc   = lane >> 4;

  __shared__ __align__(16) char hb[2][16][512];   // [parity][batch][h row, swizzled]

  // ---- weights: 32 frags = 128 VGPRs ----
  uint4 wA[4][8];
  {
    const uint4* base = WF + (size_t)((dir * 4 + q) * 128 + j * 32) * 64 + lane;
#pragma unroll
    for (int g = 0; g < 4; ++g)
#pragma unroll
      for (int kt = 0; kt < 8; ++kt)
        wA[g][kt] = base[(size_t)(g * 8 + kt) * 64];
  }

  // ---- poll setup: 3 peers x 2 entries (consecutive opairs, same batch) ----
  const int u = tid >> 4, be = tid & 15;
  const ull* pebase[3];
  uint hbw[3];
#pragma unroll
  for (int i = 0; i < 3; ++i) {
    int pm = (q + 1 + i) & 3;
    pebase[i] = EX + (size_t)(xg * 4 + pm) * 512 + u * 32 + be;   // entries +0, +16
    hbw[i] = (uint)(be * 512 + ((pm * 128 + 8 * u) ^ ((be & 7) << 4)));
  }
  ull pv[6];
#pragma unroll
  for (int i = 0; i < 6; ++i) pv[i] = 0xffffffff00000000ull;

#pragma unroll
  for (int i = 0; i < 16; ++i) ((uint*)hb)[tid + 256 * i] = 0;    // h_{-1}=0
  float cst[4] = {0.f, 0.f, 0.f, 0.f};
  __syncthreads();

  const int t0 = dir ? (Tn - 1) : 0;
  const int dstep = dir ? -1 : 1;
  const ptrdiff_t xstr = (ptrdiff_t)dstep * NC;
  const ptrdiff_t ostr = (ptrdiff_t)dstep * 512;
  const int ogb = q * 64 + j * 16 + kc * 4;       // lane's output base
  const ushort* px = xp + ((size_t)(bg * 16 + bcol) * Tn + t0) * NC + dir * 1024 + ogb;
  float* pout = out + ((size_t)(b_base + bg * 16 + bcol) * Tn + t0) * 512 + dir * 256 + ogb;
  const uint ownhb = (uint)(bcol * 512 + ((2 * ogb) ^ ((bcol & 7) << 4)));
  const size_t ex0 = (size_t)pub * 512 + (size_t)(j * 8 + kc * 2) * 16 + bcol;

  int cur = 0;
#pragma unroll 1
  for (int t = 0; t < Tn; ++t) {
    // xp for this lane's 16 gate-values (4 gates x 4 outputs), 8B loads
    ushort4 xq0 = *(const ushort4*)(px);
    ushort4 xq1 = *(const ushort4*)(px + 256);
    ushort4 xq2 = *(const ushort4*)(px + 512);
    ushort4 xq3 = *(const ushort4*)(px + 768);
    px += xstr;

    // ---- resolve 6 polls (parallel re-poll of stale entries) ----
    {
      const size_t sb = (size_t)(t & 1) * NBex;
      ull v0 = pv[0], v1 = pv[1], v2 = pv[2], v3 = pv[3], v4 = pv[4], v5 = pv[5];
      const uint tt = (uint)t;
      while (((uint)(v0 >> 32) != tt) | ((uint)(v1 >> 32) != tt) |
             ((uint)(v2 >> 32) != tt) | ((uint)(v3 >> 32) != tt) |
             ((uint)(v4 >> 32) != tt) | ((uint)(v5 >> 32) != tt)) {
        if ((uint)(v0 >> 32) != tt) v0 = exload(pebase[0] + sb);
        if ((uint)(v1 >> 32) != tt) v1 = exload(pebase[0] + sb + 16);
        if ((uint)(v2 >> 32) != tt) v2 = exload(pebase[1] + sb);
        if ((uint)(v3 >> 32) != tt) v3 = exload(pebase[1] + sb + 16);
        if ((uint)(v4 >> 32) != tt) v4 = exload(pebase[2] + sb);
        if ((uint)(v5 >> 32) != tt) v5 = exload(pebase[2] + sb + 16);
      }
      char* hbc = &hb[cur][0][0];
      *(uint2*)(hbc + hbw[0]) = (uint2){ (uint)v0, (uint)v1 };
      *(uint2*)(hbc + hbw[1]) = (uint2){ (uint)v2, (uint)v3 };
      *(uint2*)(hbc + hbw[2]) = (uint2){ (uint)v4, (uint)v5 };
    }
    barrier_lgkm();                   // full h_{t-1} in hb[cur]

    // ---- B-frags (cols = batches) + 32 MFMA in 8 chains ----
    const char* hc = &hb[cur][0][0];
    uint4 bf[8];
#pragma unroll
    for (int kt = 0; kt < 8; ++kt)
      bf[kt] = *(const uint4*)(hc + bcol * 512 + ((kt * 64 + kc * 16) ^ ((bcol & 7) << 4)));
    f32x4 aE[4], aO[4];
#pragma unroll
    for (int g = 0; g < 4; ++g) { aE[g] = (f32x4){0.f,0.f,0.f,0.f}; aO[g] = (f32x4){0.f,0.f,0.f,0.f}; }
#pragma unroll
    for (int k4 = 0; k4 < 4; ++k4)
#pragma unroll
      for (int g = 0; g < 4; ++g) {
        aE[g] = mf(wA[g][2 * k4],     bf[2 * k4],     aE[g]);
        aO[g] = mf(wA[g][2 * k4 + 1], bf[2 * k4 + 1], aO[g]);
      }

    // ---- tail: 4 cells fully in-register (D holds all 4 gates for (o,b)) ----
    float hv[4];
    const ushort* x0 = (const ushort*)&xq0;
    const ushort* x1 = (const ushort*)&xq1;
    const ushort* x2 = (const ushort*)&xq2;
    const ushort* x3 = (const ushort*)&xq3;
#pragma unroll
    for (int r = 0; r < 4; ++r) {
      float gi = aE[0][r] + aO[0][r] + h2f(x0[r]);
      float gf = aE[1][r] + aO[1][r] + h2f(x1[r]);
      float gg = aE[2][r] + aO[2][r] + h2f(x2[r]);
      float go = aE[3][r] + aO[3][r] + h2f(x3[r]);
      float iv = sig_(gi), fv = sig_(gf), gv = tanh_(gg), ov = sig_(go);
      cst[r] = fv * cst[r] + iv * gv;
      hv[r] = ov * tanh_(cst[r]);
    }
    *(float4*)pout = (float4){ hv[0], hv[1], hv[2], hv[3] };
    pout += ostr;

    uint p0 = packh(hv[0], hv[1]), p1 = packh(hv[2], hv[3]);
    *(uint2*)(&hb[cur ^ 1][0][0] + ownhb) = (uint2){ p0, p1 };   // own h for t+1
    {
      const size_t sb = (size_t)((t + 1) & 1) * NBex;
      const ull ver = (ull)(uint)(t + 1) << 32;
      __hip_atomic_store(EX + sb + ex0,      (ull)p0 | ver,
                         __ATOMIC_RELAXED, __HIP_MEMORY_SCOPE_AGENT);
      __hip_atomic_store(EX + sb + ex0 + 16, (ull)p1 | ver,
                         __ATOMIC_RELAXED, __HIP_MEMORY_SCOPE_AGENT);
      // probe next step's entries (resolved at next step's top)
#pragma unroll
      for (int i = 0; i < 3; ++i) {
        pv[2 * i]     = exload(pebase[i] + sb);
        pv[2 * i + 1] = exload(pebase[i] + sb + 16);
      }
    }
    cur ^= 1;
  }
}

// ---------------- host ----------------

extern "C" void kernel_launch(void* const* d_in, const int* in_sizes, int n_in,
                              void* d_out, int out_size, void* d_ws, size_t ws_size,
                              hipStream_t stream) {
  const float* x     = (const float*)d_in[0];
  const float* Wih_f = (const float*)d_in[1];
  const float* Whh_f = (const float*)d_in[2];
  const float* bih_f = (const float*)d_in[3];
  const float* bhh_f = (const float*)d_in[4];
  const float* Wih_b = (const float*)d_in[5];
  const float* Whh_b = (const float*)d_in[6];
  const float* bib_b = (const float*)d_in[7];
  const float* bhh_b = (const float*)d_in[8];
  float* out = (float*)d_out;

  const size_t szW16  = (size_t)NC * KT * 2;            // 2 MiB
  const size_t szBias = (size_t)NC * 4;
  const size_t szWF   = (size_t)1024 * 64 * 16;         // 1 MiB frag buffer
  const size_t szEX   = (size_t)2 * NBex * 8;           // 128 KiB exchange

  int c = 0;
  size_t szA16 = 0, szXp = 0;
  for (int cc = 1; cc <= 2; cc *= 2) {                  // batch groups need 16
    size_t a = (size_t)(Bn / cc) * Tn * KT * 2;
    size_t p = (size_t)(Bn / cc) * Tn * NC * 2;
    if (szW16 + szBias + szWF + szEX + a + p <= ws_size) { c = cc; szA16 = a; szXp = p; break; }
  }
  if (c == 0) {
    k_bad<<<(out_size + 255) / 256, 256, 0, stream>>>(out, out_size);
    return;
  }

  char* ws = (char*)d_ws;
  ushort* W16   = (ushort*)ws;
  float*  biasc = (float*)(ws + szW16);
  uint4*  WF    = (uint4*)(ws + szW16 + szBias);
  ull*    EX    = (ull*)(ws + szW16 + szBias + szWF);
  ushort* A16   = (ushort*)(ws + szW16 + szBias + szWF + szEX);
  ushort* xp    = (ushort*)(ws + szW16 + szBias + szWF + szEX + szA16);

  {
    long n4 = (long)NC * (KT / 4);
    k_prep_w<<<(int)((n4 + 255) / 256), 256, 0, stream>>>(Wih_f, Wih_b, bih_f, bhh_f,
                                                          bib_b, bhh_b, W16, biasc);
  }
  k_prep_whh<<<65536 / 256, 256, 0, stream>>>(Whh_f, Whh_b, WF);

  const int sizeB = Bn / c;          // 32 or 16
  const int nbg = sizeB / 16;        // 2 or 1
  for (int cb = 0; cb < c; ++cb) {
    const int b_base = cb * sizeB;
    {
      long nquad = (long)sizeB * Tn * KT / 4;
      k_prep_a<<<(int)((nquad + 255) / 256), 256, 0, stream>>>(
          x + (size_t)b_base * Tn * Dn, A16, nquad);
    }
    k_gemm<<<dim3(sizeB * 8 * 16), dim3(256), 0, stream>>>(A16, W16, biasc, xp);
    hipMemsetAsync(EX, 0, szEX, stream);
    k_lstm<<<dim3(32), dim3(256), 0, stream>>>(WF, xp, out, EX, b_base, nbg);
  }
}

// Round 14
// 2674.624 us; speedup vs baseline: 1.1072x; 1.0885x over previous
//
#include <hip/hip_runtime.h>
#include <cstdint>
#include <cstddef>

// Bidirectional LSTM  B=32 T=1024 D=512 H=256 (torch gate order i,f,g,o), fp32 in/out.
//
// Phase 1: xp = x @ Wih^T + bias  (fp16 MFMA GEMM, xp fp16)
// Phase 2: MFMA recurrence, 2-way M-split (R11 structure) + HYBRID exchange:
//   each versioned 8B entry {h fp32, version} is posted to EXF (plain sc0 store ->
//   producer's XCD L2; peers share that L2 via R11's same-XCD pairing) AND to EXS
//   (agent atomic -> MALL, correctness anchor). Consumers poll EXF with sc0 loads
//   (L2 RT ~300cy); every 4 failed fast polls they also check EXS (MALL) -> no hang
//   even if placement/semantics assumptions fail. Stale fast hits are benign:
//   version must match exactly, and replay determinism makes any stale
//   version-matching line bit-identical to what the producer posts.
//   Polls spread across all 8 waves (lane<16, entry w*16+n, same index as posts);
//   probe issued at previous tail. Barriers lgkmcnt-only.

typedef unsigned int   uint;
typedef unsigned short ushort;
typedef unsigned long long ull;

constexpr int Tn = 1024;
constexpr int Bn = 32;
constexpr int Dn = 512;
constexpr int Hn = 256;
constexpr int NC = 2048;          // 2 dirs * 4H
constexpr int KT = 512;           // K of the input projection
constexpr int NBmax = 128;        // max recurrence blocks (EX stride)

typedef _Float16 half8  __attribute__((ext_vector_type(8)));
typedef float    f32x4  __attribute__((ext_vector_type(4)));

__device__ __forceinline__ ushort f2h(float f) {
  _Float16 h = (_Float16)f;               // RNE
  return __builtin_bit_cast(ushort, h);
}
__device__ __forceinline__ float h2f(ushort s) {
  return (float)__builtin_bit_cast(_Float16, s);
}
__device__ __forceinline__ uint packh(float a, float b) {
  return (uint)f2h(a) | ((uint)f2h(b) << 16);
}
__device__ __forceinline__ f32x4 mf(uint4 a, uint4 b, f32x4 c) {
  return __builtin_amdgcn_mfma_f32_16x16x32_f16(
      __builtin_bit_cast(half8, a), __builtin_bit_cast(half8, b), c, 0, 0, 0);
}

__device__ __forceinline__ float sig_(float x) {
  x = fminf(fmaxf(x, -30.f), 30.f);
  return 1.f / (1.f + __expf(-x));
}
__device__ __forceinline__ float tanh_(float x) {
  x = fminf(fmaxf(x, -15.f), 15.f);
  float e = __expf(2.f * x);
  return (e - 1.f) / (e + 1.f);
}

// lgkm-only block barrier (no vmcnt drain: out/EX stores stay in flight)
__device__ __forceinline__ void barrier_lgkm() {
  asm volatile("s_waitcnt lgkmcnt(0)" ::: "memory");
  __builtin_amdgcn_s_barrier();
}

__device__ __forceinline__ ull exload(const ull* p) {          // slow: MALL
  return __hip_atomic_load(p, __ATOMIC_RELAXED, __HIP_MEMORY_SCOPE_AGENT);
}
__device__ __forceinline__ ull fastload(const ull* p) {        // fast: XCD L2
  ull v;
  asm volatile("global_load_dwordx2 %0, %1, off sc0\n\ts_waitcnt vmcnt(0)"
               : "=v"(v) : "v"(p) : "memory");
  return v;
}
__device__ __forceinline__ void faststore(ull* p, ull v) {
  asm volatile("global_store_dwordx2 %0, %1, off sc0" :: "v"(p), "v"(v) : "memory");
}

// ---------------- prep kernels ----------------

__global__ void k_prep_a(const float* __restrict__ x, ushort* __restrict__ a16, long nquad) {
  long i4 = (long)blockIdx.x * blockDim.x + threadIdx.x;
  if (i4 >= nquad) return;
  const float4 v = ((const float4*)x)[i4];
  ushort4 o;
  o.x = f2h(v.x); o.y = f2h(v.y); o.z = f2h(v.z); o.w = f2h(v.w);
  ((ushort4*)a16)[i4] = o;
}

__global__ void k_prep_w(const float* __restrict__ wf, const float* __restrict__ wb,
                         const float* __restrict__ bf1, const float* __restrict__ bf2,
                         const float* __restrict__ bb1, const float* __restrict__ bb2,
                         ushort* __restrict__ w16, float* __restrict__ biasc) {
  long i4 = (long)blockIdx.x * blockDim.x + threadIdx.x;
  if (i4 >= (long)NC * (KT / 4)) return;
  int n = (int)(i4 >> 7);
  int k4 = (int)(i4 & 127);
  int dir = n >> 10, g = n & 1023;
  const float* w = dir ? wb : wf;
  const float4 v = ((const float4*)(w + (size_t)g * Dn))[k4];
  ushort4 o;
  o.x = f2h(v.x); o.y = f2h(v.y); o.z = f2h(v.z); o.w = f2h(v.w);
  ((ushort4*)w16)[i4] = o;
  if (k4 == 0) biasc[n] = dir ? (bb1[g] + bb2[g]) : (bf1[g] + bf2[g]);
}

// Whh -> A-frags in per-(dir,half,wave) consumption order.
// frag = ((dir*2+half)*8 + w)*32 + p*4 + g ; phase p=0..7 (local kts first):
// ktphys = (p + 4*half) & 7 ; row = g*256 + half*128 + w*16 + (lane&15);
// k = ktphys*32 + (lane>>4)*8.
__global__ void k_prep_whh(const float* __restrict__ whhF, const float* __restrict__ whhB,
                           uint4* __restrict__ WF) {
  int t = blockIdx.x * blockDim.x + threadIdx.x;   // 0 .. 1024*64-1
  if (t >= 1024 * 64) return;
  int lane = t & 63;
  int frag = t >> 6;
  int g    = frag & 3;
  int p    = (frag >> 2) & 7;
  int w    = (frag >> 5) & 7;
  int half = (frag >> 8) & 1;
  int dir  = (frag >> 9) & 1;
  int row = g * 256 + half * 128 + w * 16 + (lane & 15);
  int ktphys = (p + 4 * half) & 7;
  int kb = ktphys * 32 + (lane >> 4) * 8;
  const float* whh = dir ? whhB : whhF;
  const float4* s = (const float4*)(whh + (size_t)row * Hn + kb);
  float4 v0 = s[0], v1 = s[1];
  WF[t] = (uint4){ packh(v0.x, v0.y), packh(v0.z, v0.w),
                   packh(v1.x, v1.y), packh(v1.z, v1.w) };
}

__global__ void k_bad(float* __restrict__ out, int n) {
  int i = blockIdx.x * blockDim.x + threadIdx.x;
  if (i < n) out[i] = 54321.f;
}

// ---------------- phase 1: fp16 MFMA GEMM (unchanged) ----------------

__device__ __forceinline__ void gload_lds16(const void* g, void* l) {
  __builtin_amdgcn_global_load_lds((const __attribute__((address_space(1))) void*)g,
                                   (__attribute__((address_space(3))) void*)l, 16, 0, 0);
}

__global__ __launch_bounds__(256) void k_gemm(const ushort* __restrict__ A,
                                              const ushort* __restrict__ W,
                                              const float* __restrict__ biasc,
                                              ushort* __restrict__ xp) {
  __shared__ __align__(16) ushort As[128 * 32];
  __shared__ __align__(16) ushort Bs[128 * 32];
  const int bid = blockIdx.x;
  const int m0 = (bid >> 4) * 128;
  const int n0 = (bid & 15) * 128;
  const int tid = threadIdx.x;
  const int wid = tid >> 6, lane = tid & 63;
  const int wr = wid >> 1, wcq = wid & 1;
  const int l16 = lane & 15, lq = lane >> 4;

  f32x4 acc[4][4] = {};

  for (int kt = 0; kt < KT; kt += 32) {
    __syncthreads();
#pragma unroll
    for (int i = 0; i < 2; ++i) {
      int ch = wid * 2 + i;
      int p = ch * 64 + lane;
      int r = p >> 2, gp = p & 3;
      int gs = gp ^ ((r >> 1) & 3);
      gload_lds16(A + (size_t)(m0 + r) * KT + kt + gs * 8, (char*)As + ch * 1024);
      gload_lds16(W + (size_t)(n0 + r) * KT + kt + gs * 8, (char*)Bs + ch * 1024);
    }
    __syncthreads();

    half8 af[4], bfr[4];
#pragma unroll
    for (int mfi = 0; mfi < 4; ++mfi) {
      int row = wr * 64 + mfi * 16 + l16;
      int g = lq ^ ((row >> 1) & 3);
      af[mfi] = *(const half8*)((const char*)As + row * 64 + g * 16);
    }
#pragma unroll
    for (int nf = 0; nf < 4; ++nf) {
      int row = wcq * 64 + nf * 16 + l16;
      int g = lq ^ ((row >> 1) & 3);
      bfr[nf] = *(const half8*)((const char*)Bs + row * 64 + g * 16);
    }
#pragma unroll
    for (int mfi = 0; mfi < 4; ++mfi)
#pragma unroll
      for (int nf = 0; nf < 4; ++nf)
        acc[mfi][nf] = __builtin_amdgcn_mfma_f32_16x16x32_f16(af[mfi], bfr[nf], acc[mfi][nf], 0, 0, 0);
  }

#pragma unroll
  for (int nf = 0; nf < 4; ++nf) {
    int col = n0 + wcq * 64 + nf * 16 + l16;
    float bv = biasc[col];
#pragma unroll
    for (int mfi = 0; mfi < 4; ++mfi) {
      int rbase = m0 + wr * 64 + mfi * 16 + lq * 4;
#pragma unroll
      for (int i = 0; i < 4; ++i)
        xp[(size_t)(rbase + i) * NC + col] = f2h(acc[mfi][nf][i] + bv);
    }
  }
}

// ---------------- phase 2: M-split recurrence, hybrid exchange ----------------
// bid = half*pairStride + p ; p = (bl<<1)|dir ; peer = bid ^ pairStride.
// EX[slot][bid][out]: {lo32: h fp32 bits, hi32: version}. Step t consumes version t
// from slot t&1 (probed at previous tail, fast path first); posts version t+1 to
// slot (t+1)&1 in BOTH EXF (sc0/L2) and EXS (agent/MALL).

__global__ __launch_bounds__(512, 2) void k_lstm(const uint4* __restrict__ WF,
                                                 const ushort* __restrict__ xp,
                                                 float* __restrict__ out,
                                                 ull* __restrict__ EXS,
                                                 ull* __restrict__ EXF,
                                                 int b_base, int pairStride) {
  const int bid  = blockIdx.x;
  const int half = (bid & pairStride) ? 1 : 0;
  const int p_   = bid & (pairStride - 1);
  const int dir  = p_ & 1;
  const int bl   = p_ >> 1;
  const int tid  = threadIdx.x;
  const int w    = tid >> 6;
  const int lane = tid & 63;
  const int lq   = lane >> 4;
  const int n    = lane & 15;          // output within wave (4x lane-redundant)

  __shared__ ushort hp[2][256];        // full h (both halves), double-buffered
  __shared__ float  gbuf[8][4][16];    // gate bounce

  // ---- persistent weights: 32 frags, all registers, consumption order ----
  const uint4* wfb = WF + (size_t)(((dir * 2 + half) * 8 + w) * 32) * 64 + lane;
  uint4 wA[32];
#pragma unroll
  for (int f = 0; f < 32; ++f) wA[f] = wfb[(size_t)f * 64];

  if (tid < 256) { hp[0][tid] = 0; hp[1][tid] = 0; }
  float creg = 0.f;
  __syncthreads();

  const int dstep = dir ? -1 : 1;
  const int t0 = dir ? (Tn - 1) : 0;
  const ptrdiff_t xstr = (ptrdiff_t)dstep * NC;
  const ptrdiff_t ostr = (ptrdiff_t)dstep * 512;
  const ushort* px = xp + (size_t)(bl * Tn + t0) * NC + dir * 1024 + half * 128 + w * 16 + n;
  float* pout = out + (size_t)((b_base + bl) * Tn + t0) * 512 + dir * 256 + half * 128 + w * 16 + n;

  const size_t myoff   = (size_t)bid * 128 + w * 16 + n;
  const size_t peeroff = (size_t)(bid ^ pairStride) * 128 + w * 16 + n;
  ull* exwS = EXS + myoff;
  ull* exwF = EXF + myoff;
  const ull* prdS = EXS + peeroff;
  const ull* prdF = EXF + peeroff;
  const int rbase = (half ^ 1) * 128;                                // remote half in hp

  int cur = 0;
  ull pv = 0xffffffff00000000ull;
  if (lane < 16) pv = fastload(prdF);          // pre-probe for t=0 (slot 0)

#pragma unroll 1
  for (int t = 0; t < Tn; ++t) {
    // xp for this lane's 4 gates (consumed in tail; latency hidden)
    ushort xg0 = px[0], xg1 = px[256], xg2 = px[512], xg3 = px[768];
    px += xstr;

    f32x4 acc0 = {0.f,0.f,0.f,0.f}, acc1 = {0.f,0.f,0.f,0.f};
    f32x4 acc2 = {0.f,0.f,0.f,0.f}, acc3 = {0.f,0.f,0.f,0.f};

    // ---- phase 1: local kts (p=0..3); probe flight continues under these ----
    const char* hb = (const char*)hp[cur];
    const int kb0 = (4 * half) * 64;   // local kt byte base (wraps within 512)
#pragma unroll
    for (int p = 0; p < 4; ++p) {
      uint4 b = *(const uint4*)(hb + ((kb0 + p * 64) & 511) + lq * 16);
      acc0 = mf(wA[p * 4 + 0], b, acc0);
      acc1 = mf(wA[p * 4 + 1], b, acc1);
      acc2 = mf(wA[p * 4 + 2], b, acc2);
      acc3 = mf(wA[p * 4 + 3], b, acc3);
    }

    if (lane < 16) {                   // resolve: fast path, MALL fallback
      ull v = pv;
      if ((uint)(v >> 32) != (uint)t) {
        const size_t so = (size_t)(t & 1) * NBmax * 128;
        const ull* pf = prdF + so;
        const ull* ps = prdS + so;
        int spins = 0;
        for (;;) {
          v = fastload(pf);
          if ((uint)(v >> 32) == (uint)t) break;
          if (++spins >= 4) {
            v = exload(ps);
            if ((uint)(v >> 32) == (uint)t) break;
          }
        }
      }
      hp[cur][rbase + w * 16 + n] = f2h(__builtin_bit_cast(float, (uint)v));
    }
    barrier_lgkm();                    // remote half of h_{t-1} now in hp[cur]

    // ---- phase 2: remote kts (p=4..7) ----
    const int kb1 = (4 * (half ^ 1)) * 64;
#pragma unroll
    for (int p = 0; p < 4; ++p) {
      uint4 b = *(const uint4*)(hb + ((kb1 + p * 64) & 511) + lq * 16);
      acc0 = mf(wA[16 + p * 4 + 0], b, acc0);
      acc1 = mf(wA[16 + p * 4 + 1], b, acc1);
      acc2 = mf(wA[16 + p * 4 + 2], b, acc2);
      acc3 = mf(wA[16 + p * 4 + 3], b, acc3);
    }

    // ---- tail: bounce D col0 rows, activate, post h (EX first), probe next ----
    if ((lane & 15) == 0) {
      *(f32x4*)&gbuf[w][0][lq * 4] = acc0;
      *(f32x4*)&gbuf[w][1][lq * 4] = acc1;
      *(f32x4*)&gbuf[w][2][lq * 4] = acc2;
      *(f32x4*)&gbuf[w][3][lq * 4] = acc3;
    }
    // in-wave LDS dependency (compiler inserts lgkmcnt)
    float gi = gbuf[w][0][n] + h2f(xg0);
    float gf = gbuf[w][1][n] + h2f(xg1);
    float gg = gbuf[w][2][n] + h2f(xg2);
    float go = gbuf[w][3][n] + h2f(xg3);
    float iv = sig_(gi), fv = sig_(gf), gv = tanh_(gg), ov = sig_(go);
    creg = fv * creg + iv * gv;
    float h = ov * tanh_(creg);
    if (lane < 16) {
      const size_t so = (size_t)((t + 1) & 1) * NBmax * 128;
      ull pk = (ull)__builtin_bit_cast(uint, h) | ((ull)(uint)(t + 1) << 32);
      faststore(exwF + so, pk);
      __hip_atomic_store(exwS + so, pk, __ATOMIC_RELAXED, __HIP_MEMORY_SCOPE_AGENT);
      *pout = h;
      hp[cur ^ 1][half * 128 + w * 16 + n] = f2h(h);
      pv = fastload(prdF + so);        // probe next step's entry (version t+1)
    }
    pout += ostr;
    barrier_lgkm();                    // local half of h_t visible to all waves
    cur ^= 1;
  }
}

// ---------------- host ----------------

extern "C" void kernel_launch(void* const* d_in, const int* in_sizes, int n_in,
                              void* d_out, int out_size, void* d_ws, size_t ws_size,
                              hipStream_t stream) {
  const float* x     = (const float*)d_in[0];
  const float* Wih_f = (const float*)d_in[1];
  const float* Whh_f = (const float*)d_in[2];
  const float* bih_f = (const float*)d_in[3];
  const float* bhh_f = (const float*)d_in[4];
  const float* Wih_b = (const float*)d_in[5];
  const float* Whh_b = (const float*)d_in[6];
  const float* bib_b = (const float*)d_in[7];
  const float* bhh_b = (const float*)d_in[8];
  float* out = (float*)d_out;

  const size_t szW16  = (size_t)NC * KT * 2;            // 2 MiB
  const size_t szBias = (size_t)NC * 4;
  const size_t szWF   = (size_t)1024 * 64 * 16;         // 1 MiB frag buffer
  const size_t szEX   = (size_t)2 * NBmax * 128 * 8;    // 256 KiB per exchange buffer

  int c = 0;
  size_t szA16 = 0, szXp = 0;
  for (int cc = 1; cc <= 16; cc *= 2) {
    size_t a = (size_t)(Bn / cc) * Tn * KT * 2;
    size_t p = (size_t)(Bn / cc) * Tn * NC * 2;
    if (szW16 + szBias + szWF + 2 * szEX + a + p <= ws_size) { c = cc; szA16 = a; szXp = p; break; }
  }
  if (c == 0) {
    k_bad<<<(out_size + 255) / 256, 256, 0, stream>>>(out, out_size);
    return;
  }

  char* ws = (char*)d_ws;
  ushort* W16   = (ushort*)ws;
  float*  biasc = (float*)(ws + szW16);
  uint4*  WF    = (uint4*)(ws + szW16 + szBias);
  ull*    EXS   = (ull*)(ws + szW16 + szBias + szWF);
  ull*    EXF   = (ull*)(ws + szW16 + szBias + szWF + szEX);
  ushort* A16   = (ushort*)(ws + szW16 + szBias + szWF + 2 * szEX);
  ushort* xp    = (ushort*)(ws + szW16 + szBias + szWF + 2 * szEX + szA16);

  {
    long n4 = (long)NC * (KT / 4);
    k_prep_w<<<(int)((n4 + 255) / 256), 256, 0, stream>>>(Wih_f, Wih_b, bih_f, bhh_f,
                                                          bib_b, bhh_b, W16, biasc);
  }
  k_prep_whh<<<(1024 * 64) / 256, 256, 0, stream>>>(Whh_f, Whh_b, WF);

  const int sizeB = Bn / c;
  const int pairStride = 2 * sizeB;    // peers bid and bid^pairStride share an XCD
  for (int cb = 0; cb < c; ++cb) {
    const int b_base = cb * sizeB;
    {
      long nquad = (long)sizeB * Tn * KT / 4;
      k_prep_a<<<(int)((nquad + 255) / 256), 256, 0, stream>>>(
          x + (size_t)b_base * Tn * Dn, A16, nquad);
    }
    k_gemm<<<dim3(sizeB * 8 * 16), dim3(256), 0, stream>>>(A16, W16, biasc, xp);
    hipMemsetAsync(EXS, 0, szEX, stream);
    hipMemsetAsync(EXF, 0, szEX, stream);
    k_lstm<<<dim3(4 * sizeB), dim3(512), 0, stream>>>(WF, xp, out, EXS, EXF,
                                                      b_base, pairStride);
  }
}

// Round 15
// 1565.536 us; speedup vs baseline: 1.8915x; 1.7084x over previous
//
#include <hip/hip_runtime.h>
#include <cstdint>
#include <cstddef>

// Bidirectional LSTM  B=32 T=1024 D=512 H=256 (torch gate order i,f,g,o), fp32 in/out.
//
// Phase 1: xp = x @ Wih^T + bias  (fp16 MFMA GEMM, xp fp16)
// Phase 2: MFMA recurrence, 2-way M-split (R11 structure, 1355us proven).
//   bid = half*pairStride + p, peer = bid ^ pairStride (same-XCD under round-robin;
//   perf heuristic only). Block owns 512 gate rows = 128 outputs; 8 waves; all 32
//   A-frags/wave in REGISTERS. Exchange: 8B agent-atomic entries {h fp32, version},
//   parity double-buffered EX[2].
//   KEY CHANGE vs R11: the probe for step t+1 is issued at step t's TAIL (right
//   after posting), carried in a register (pv); the compiler defers its waitcnt to
//   first use at step t+1's resolve (after phase-1) -> flight time ~= tail + barrier
//   + phase-1 ~= 1100cy vs R11's 620 -> exposed MALL RT ~300cy instead of ~780.
//   (R14's regression was inline-asm s_waitcnt vmcnt(0) at probe ISSUE, which
//   drained the tail stores every step. No asm here; plain atomic loads.)

typedef unsigned int   uint;
typedef unsigned short ushort;
typedef unsigned long long ull;

constexpr int Tn = 1024;
constexpr int Bn = 32;
constexpr int Dn = 512;
constexpr int Hn = 256;
constexpr int NC = 2048;          // 2 dirs * 4H
constexpr int KT = 512;           // K of the input projection
constexpr int NBmax = 128;        // max recurrence blocks (EX stride)

typedef _Float16 half8  __attribute__((ext_vector_type(8)));
typedef float    f32x4  __attribute__((ext_vector_type(4)));

__device__ __forceinline__ ushort f2h(float f) {
  _Float16 h = (_Float16)f;               // RNE
  return __builtin_bit_cast(ushort, h);
}
__device__ __forceinline__ float h2f(ushort s) {
  return (float)__builtin_bit_cast(_Float16, s);
}
__device__ __forceinline__ uint packh(float a, float b) {
  return (uint)f2h(a) | ((uint)f2h(b) << 16);
}
__device__ __forceinline__ f32x4 mf(uint4 a, uint4 b, f32x4 c) {
  return __builtin_amdgcn_mfma_f32_16x16x32_f16(
      __builtin_bit_cast(half8, a), __builtin_bit_cast(half8, b), c, 0, 0, 0);
}

__device__ __forceinline__ float sig_(float x) {
  x = fminf(fmaxf(x, -30.f), 30.f);
  return 1.f / (1.f + __expf(-x));
}
__device__ __forceinline__ float tanh_(float x) {
  x = fminf(fmaxf(x, -15.f), 15.f);
  float e = __expf(2.f * x);
  return (e - 1.f) / (e + 1.f);
}

// lgkm-only block barrier (no vmcnt drain: out/EX stores stay in flight)
__device__ __forceinline__ void barrier_lgkm() {
  asm volatile("s_waitcnt lgkmcnt(0)" ::: "memory");
  __builtin_amdgcn_s_barrier();
}

__device__ __forceinline__ ull exload(const ull* p) {
  return __hip_atomic_load(p, __ATOMIC_RELAXED, __HIP_MEMORY_SCOPE_AGENT);
}

// ---------------- prep kernels ----------------

__global__ void k_prep_a(const float* __restrict__ x, ushort* __restrict__ a16, long nquad) {
  long i4 = (long)blockIdx.x * blockDim.x + threadIdx.x;
  if (i4 >= nquad) return;
  const float4 v = ((const float4*)x)[i4];
  ushort4 o;
  o.x = f2h(v.x); o.y = f2h(v.y); o.z = f2h(v.z); o.w = f2h(v.w);
  ((ushort4*)a16)[i4] = o;
}

__global__ void k_prep_w(const float* __restrict__ wf, const float* __restrict__ wb,
                         const float* __restrict__ bf1, const float* __restrict__ bf2,
                         const float* __restrict__ bb1, const float* __restrict__ bb2,
                         ushort* __restrict__ w16, float* __restrict__ biasc) {
  long i4 = (long)blockIdx.x * blockDim.x + threadIdx.x;
  if (i4 >= (long)NC * (KT / 4)) return;
  int n = (int)(i4 >> 7);
  int k4 = (int)(i4 & 127);
  int dir = n >> 10, g = n & 1023;
  const float* w = dir ? wb : wf;
  const float4 v = ((const float4*)(w + (size_t)g * Dn))[k4];
  ushort4 o;
  o.x = f2h(v.x); o.y = f2h(v.y); o.z = f2h(v.z); o.w = f2h(v.w);
  ((ushort4*)w16)[i4] = o;
  if (k4 == 0) biasc[n] = dir ? (bb1[g] + bb2[g]) : (bf1[g] + bf2[g]);
}

// Whh -> A-frags in per-(dir,half,wave) consumption order.
// frag = ((dir*2+half)*8 + w)*32 + p*4 + g ; phase p=0..7 (local kts first):
// ktphys = (p + 4*half) & 7 ; row = g*256 + half*128 + w*16 + (lane&15);
// k = ktphys*32 + (lane>>4)*8.
__global__ void k_prep_whh(const float* __restrict__ whhF, const float* __restrict__ whhB,
                           uint4* __restrict__ WF) {
  int t = blockIdx.x * blockDim.x + threadIdx.x;   // 0 .. 1024*64-1
  if (t >= 1024 * 64) return;
  int lane = t & 63;
  int frag = t >> 6;
  int g    = frag & 3;
  int p    = (frag >> 2) & 7;
  int w    = (frag >> 5) & 7;
  int half = (frag >> 8) & 1;
  int dir  = (frag >> 9) & 1;
  int row = g * 256 + half * 128 + w * 16 + (lane & 15);
  int ktphys = (p + 4 * half) & 7;
  int kb = ktphys * 32 + (lane >> 4) * 8;
  const float* whh = dir ? whhB : whhF;
  const float4* s = (const float4*)(whh + (size_t)row * Hn + kb);
  float4 v0 = s[0], v1 = s[1];
  WF[t] = (uint4){ packh(v0.x, v0.y), packh(v0.z, v0.w),
                   packh(v1.x, v1.y), packh(v1.z, v1.w) };
}

__global__ void k_bad(float* __restrict__ out, int n) {
  int i = blockIdx.x * blockDim.x + threadIdx.x;
  if (i < n) out[i] = 54321.f;
}

// ---------------- phase 1: fp16 MFMA GEMM (unchanged) ----------------

__device__ __forceinline__ void gload_lds16(const void* g, void* l) {
  __builtin_amdgcn_global_load_lds((const __attribute__((address_space(1))) void*)g,
                                   (__attribute__((address_space(3))) void*)l, 16, 0, 0);
}

__global__ __launch_bounds__(256) void k_gemm(const ushort* __restrict__ A,
                                              const ushort* __restrict__ W,
                                              const float* __restrict__ biasc,
                                              ushort* __restrict__ xp) {
  __shared__ __align__(16) ushort As[128 * 32];
  __shared__ __align__(16) ushort Bs[128 * 32];
  const int bid = blockIdx.x;
  const int m0 = (bid >> 4) * 128;
  const int n0 = (bid & 15) * 128;
  const int tid = threadIdx.x;
  const int wid = tid >> 6, lane = tid & 63;
  const int wr = wid >> 1, wcq = wid & 1;
  const int l16 = lane & 15, lq = lane >> 4;

  f32x4 acc[4][4] = {};

  for (int kt = 0; kt < KT; kt += 32) {
    __syncthreads();
#pragma unroll
    for (int i = 0; i < 2; ++i) {
      int ch = wid * 2 + i;
      int p = ch * 64 + lane;
      int r = p >> 2, gp = p & 3;
      int gs = gp ^ ((r >> 1) & 3);
      gload_lds16(A + (size_t)(m0 + r) * KT + kt + gs * 8, (char*)As + ch * 1024);
      gload_lds16(W + (size_t)(n0 + r) * KT + kt + gs * 8, (char*)Bs + ch * 1024);
    }
    __syncthreads();

    half8 af[4], bfr[4];
#pragma unroll
    for (int mfi = 0; mfi < 4; ++mfi) {
      int row = wr * 64 + mfi * 16 + l16;
      int g = lq ^ ((row >> 1) & 3);
      af[mfi] = *(const half8*)((const char*)As + row * 64 + g * 16);
    }
#pragma unroll
    for (int nf = 0; nf < 4; ++nf) {
      int row = wcq * 64 + nf * 16 + l16;
      int g = lq ^ ((row >> 1) & 3);
      bfr[nf] = *(const half8*)((const char*)Bs + row * 64 + g * 16);
    }
#pragma unroll
    for (int mfi = 0; mfi < 4; ++mfi)
#pragma unroll
      for (int nf = 0; nf < 4; ++nf)
        acc[mfi][nf] = __builtin_amdgcn_mfma_f32_16x16x32_f16(af[mfi], bfr[nf], acc[mfi][nf], 0, 0, 0);
  }

#pragma unroll
  for (int nf = 0; nf < 4; ++nf) {
    int col = n0 + wcq * 64 + nf * 16 + l16;
    float bv = biasc[col];
#pragma unroll
    for (int mfi = 0; mfi < 4; ++mfi) {
      int rbase = m0 + wr * 64 + mfi * 16 + lq * 4;
#pragma unroll
      for (int i = 0; i < 4; ++i)
        xp[(size_t)(rbase + i) * NC + col] = f2h(acc[mfi][nf][i] + bv);
    }
  }
}

// ---------------- phase 2: M-split recurrence, tail-probed exchange ----------------
// bid = half*pairStride + p ; p = (bl<<1)|dir ; peer = bid ^ pairStride.
// EX[slot][bid][out]: {lo32: h fp32 bits, hi32: version}. Step t consumes version t
// from slot t&1; probe for t+1 issued at step t's tail (after posting), resolved
// after step t+1's phase-1.

__global__ __launch_bounds__(512, 2) void k_lstm(const uint4* __restrict__ WF,
                                                 const ushort* __restrict__ xp,
                                                 float* __restrict__ out,
                                                 ull* __restrict__ EX,
                                                 int b_base, int pairStride) {
  const int bid  = blockIdx.x;
  const int half = (bid & pairStride) ? 1 : 0;
  const int p_   = bid & (pairStride - 1);
  const int dir  = p_ & 1;
  const int bl   = p_ >> 1;
  const int tid  = threadIdx.x;
  const int w    = tid >> 6;
  const int lane = tid & 63;
  const int lq   = lane >> 4;
  const int n    = lane & 15;          // output within wave (4x lane-redundant)

  __shared__ ushort hp[2][256];        // full h (both halves), double-buffered
  __shared__ float  gbuf[8][4][16];    // gate bounce

  // ---- persistent weights: 32 frags, all registers, consumption order ----
  const uint4* wfb = WF + (size_t)(((dir * 2 + half) * 8 + w) * 32) * 64 + lane;
  uint4 wA[32];
#pragma unroll
  for (int f = 0; f < 32; ++f) wA[f] = wfb[(size_t)f * 64];

  if (tid < 256) { hp[0][tid] = 0; hp[1][tid] = 0; }
  float creg = 0.f;
  __syncthreads();

  const int dstep = dir ? -1 : 1;
  const int t0 = dir ? (Tn - 1) : 0;
  const ptrdiff_t xstr = (ptrdiff_t)dstep * NC;
  const ptrdiff_t ostr = (ptrdiff_t)dstep * 512;
  const ushort* px = xp + (size_t)(bl * Tn + t0) * NC + dir * 1024 + half * 128 + w * 16 + n;
  float* pout = out + (size_t)((b_base + bl) * Tn + t0) * 512 + dir * 256 + half * 128 + w * 16 + n;

  const size_t myoff   = (size_t)bid * 128 + w * 16 + n;
  const size_t peeroff = (size_t)(bid ^ pairStride) * 128 + w * 16 + n;
  ull* exw = EX + myoff;
  const ull* prd = EX + peeroff;
  const int rbase = (half ^ 1) * 128;                                // remote half in hp

  int cur = 0;
  ull pv = 0xffffffff00000000ull;
  if (lane < 16) pv = exload(prd);             // probe for t=0 (slot 0, version 0)

#pragma unroll 1
  for (int t = 0; t < Tn; ++t) {
    // xp for this lane's 4 gates (consumed in tail; latency hidden)
    ushort xg0 = px[0], xg1 = px[256], xg2 = px[512], xg3 = px[768];
    px += xstr;

    f32x4 acc0 = {0.f,0.f,0.f,0.f}, acc1 = {0.f,0.f,0.f,0.f};
    f32x4 acc2 = {0.f,0.f,0.f,0.f}, acc3 = {0.f,0.f,0.f,0.f};

    // ---- phase 1: local kts (p=0..3); probe (issued at prev tail) in flight ----
    const char* hb = (const char*)hp[cur];
    const int kb0 = (4 * half) * 64;   // local kt byte base (wraps within 512)
#pragma unroll
    for (int p = 0; p < 4; ++p) {
      uint4 b = *(const uint4*)(hb + ((kb0 + p * 64) & 511) + lq * 16);
      acc0 = mf(wA[p * 4 + 0], b, acc0);
      acc1 = mf(wA[p * 4 + 1], b, acc1);
      acc2 = mf(wA[p * 4 + 2], b, acc2);
      acc3 = mf(wA[p * 4 + 3], b, acc3);
    }

    if (lane < 16) {                   // resolve (spin only if probe was stale)
      ull v = pv;
      const ull* pe = prd + (size_t)(t & 1) * NBmax * 128;
      while ((uint)(v >> 32) != (uint)t)
        v = exload(pe);
      hp[cur][rbase + w * 16 + n] = f2h(__builtin_bit_cast(float, (uint)v));
    }
    barrier_lgkm();                    // remote half of h_{t-1} now in hp[cur]

    // ---- phase 2: remote kts (p=4..7) ----
    const int kb1 = (4 * (half ^ 1)) * 64;
#pragma unroll
    for (int p = 0; p < 4; ++p) {
      uint4 b = *(const uint4*)(hb + ((kb1 + p * 64) & 511) + lq * 16);
      acc0 = mf(wA[16 + p * 4 + 0], b, acc0);
      acc1 = mf(wA[16 + p * 4 + 1], b, acc1);
      acc2 = mf(wA[16 + p * 4 + 2], b, acc2);
      acc3 = mf(wA[16 + p * 4 + 3], b, acc3);
    }

    // ---- tail: bounce D col0 rows, activate, post h, then PROBE next step ----
    if ((lane & 15) == 0) {
      *(f32x4*)&gbuf[w][0][lq * 4] = acc0;
      *(f32x4*)&gbuf[w][1][lq * 4] = acc1;
      *(f32x4*)&gbuf[w][2][lq * 4] = acc2;
      *(f32x4*)&gbuf[w][3][lq * 4] = acc3;
    }
    // in-wave LDS dependency (compiler inserts lgkmcnt)
    float gi = gbuf[w][0][n] + h2f(xg0);
    float gf = gbuf[w][1][n] + h2f(xg1);
    float gg = gbuf[w][2][n] + h2f(xg2);
    float go = gbuf[w][3][n] + h2f(xg3);
    float iv = sig_(gi), fv = sig_(gf), gv = tanh_(gg), ov = sig_(go);
    creg = fv * creg + iv * gv;
    float h = ov * tanh_(creg);
    if (lane < 16) {
      const size_t so = (size_t)((t + 1) & 1) * NBmax * 128;
      ull pk = (ull)__builtin_bit_cast(uint, h) | ((ull)(uint)(t + 1) << 32);
      __hip_atomic_store(exw + so, pk, __ATOMIC_RELAXED, __HIP_MEMORY_SCOPE_AGENT);
      *pout = h;
      hp[cur ^ 1][half * 128 + w * 16 + n] = f2h(h);
      pv = exload(prd + so);           // probe next step's entry; waitcnt deferred
    }                                  // to next step's resolve (first use)
    pout += ostr;
    barrier_lgkm();                    // local half of h_t visible to all waves
    cur ^= 1;
  }
}

// ---------------- host ----------------

extern "C" void kernel_launch(void* const* d_in, const int* in_sizes, int n_in,
                              void* d_out, int out_size, void* d_ws, size_t ws_size,
                              hipStream_t stream) {
  const float* x     = (const float*)d_in[0];
  const float* Wih_f = (const float*)d_in[1];
  const float* Whh_f = (const float*)d_in[2];
  const float* bih_f = (const float*)d_in[3];
  const float* bhh_f = (const float*)d_in[4];
  const float* Wih_b = (const float*)d_in[5];
  const float* Whh_b = (const float*)d_in[6];
  const float* bib_b = (const float*)d_in[7];
  const float* bhh_b = (const float*)d_in[8];
  float* out = (float*)d_out;

  const size_t szW16  = (size_t)NC * KT * 2;            // 2 MiB
  const size_t szBias = (size_t)NC * 4;
  const size_t szWF   = (size_t)1024 * 64 * 16;         // 1 MiB frag buffer
  const size_t szEX   = (size_t)2 * NBmax * 128 * 8;    // 256 KiB exchange

  int c = 0;
  size_t szA16 = 0, szXp = 0;
  for (int cc = 1; cc <= 16; cc *= 2) {
    size_t a = (size_t)(Bn / cc) * Tn * KT * 2;
    size_t p = (size_t)(Bn / cc) * Tn * NC * 2;
    if (szW16 + szBias + szWF + szEX + a + p <= ws_size) { c = cc; szA16 = a; szXp = p; break; }
  }
  if (c == 0) {
    k_bad<<<(out_size + 255) / 256, 256, 0, stream>>>(out, out_size);
    return;
  }

  char* ws = (char*)d_ws;
  ushort* W16   = (ushort*)ws;
  float*  biasc = (float*)(ws + szW16);
  uint4*  WF    = (uint4*)(ws + szW16 + szBias);
  ull*    EX    = (ull*)(ws + szW16 + szBias + szWF);
  ushort* A16   = (ushort*)(ws + szW16 + szBias + szWF + szEX);
  ushort* xp    = (ushort*)(ws + szW16 + szBias + szWF + szEX + szA16);

  {
    long n4 = (long)NC * (KT / 4);
    k_prep_w<<<(int)((n4 + 255) / 256), 256, 0, stream>>>(Wih_f, Wih_b, bih_f, bhh_f,
                                                          bib_b, bhh_b, W16, biasc);
  }
  k_prep_whh<<<(1024 * 64) / 256, 256, 0, stream>>>(Whh_f, Whh_b, WF);

  const int sizeB = Bn / c;
  const int pairStride = 2 * sizeB;    // peers bid and bid^pairStride share an XCD
  for (int cb = 0; cb < c; ++cb) {
    const int b_base = cb * sizeB;
    {
      long nquad = (long)sizeB * Tn * KT / 4;
      k_prep_a<<<(int)((nquad + 255) / 256), 256, 0, stream>>>(
          x + (size_t)b_base * Tn * Dn, A16, nquad);
    }
    k_gemm<<<dim3(sizeB * 8 * 16), dim3(256), 0, stream>>>(A16, W16, biasc, xp);
    hipMemsetAsync(EX, 0, szEX, stream);
    k_lstm<<<dim3(4 * sizeB), dim3(512), 0, stream>>>(WF, xp, out, EX, b_base, pairStride);
  }
}

// Round 16
// 1490.842 us; speedup vs baseline: 1.9863x; 1.0501x over previous
//
#include <hip/hip_runtime.h>
#include <cstdint>
#include <cstddef>

// Bidirectional LSTM  B=32 T=1024 D=512 H=256 (torch gate order i,f,g,o), fp32 in/out.
//
// Phase 1: xp = x @ Wih^T + bias  (fp16 MFMA GEMM, xp fp16)
// Phase 2: MFMA recurrence, 2-way M-split (R11 structure, 1355us proven) + PROBE
//   LADDER: three staggered relaxed-atomic probes per step --
//   pv0 issued at the PREVIOUS tail BEFORE the EX/out stores (in-order vmcnt
//   retirement -> pv0 retires without waiting the ~1400cy MALL store-acks; R15's
//   regression was probing AFTER the stores), pv1 at step start, pv2 mid-phase-1.
//   Resolve tries pv0 -> pv1 -> pv2 -> spin. Compiler emits counted vmcnt per rung
//   (newer probes outstanding), so early rungs never drain later ops. No inline-asm
//   loads (R14's lesson). Everything else byte-identical to R11.

typedef unsigned int   uint;
typedef unsigned short ushort;
typedef unsigned long long ull;

constexpr int Tn = 1024;
constexpr int Bn = 32;
constexpr int Dn = 512;
constexpr int Hn = 256;
constexpr int NC = 2048;          // 2 dirs * 4H
constexpr int KT = 512;           // K of the input projection
constexpr int NBmax = 128;        // max recurrence blocks (EX stride)

typedef _Float16 half8  __attribute__((ext_vector_type(8)));
typedef float    f32x4  __attribute__((ext_vector_type(4)));

__device__ __forceinline__ ushort f2h(float f) {
  _Float16 h = (_Float16)f;               // RNE
  return __builtin_bit_cast(ushort, h);
}
__device__ __forceinline__ float h2f(ushort s) {
  return (float)__builtin_bit_cast(_Float16, s);
}
__device__ __forceinline__ uint packh(float a, float b) {
  return (uint)f2h(a) | ((uint)f2h(b) << 16);
}
__device__ __forceinline__ f32x4 mf(uint4 a, uint4 b, f32x4 c) {
  return __builtin_amdgcn_mfma_f32_16x16x32_f16(
      __builtin_bit_cast(half8, a), __builtin_bit_cast(half8, b), c, 0, 0, 0);
}

__device__ __forceinline__ float sig_(float x) {
  x = fminf(fmaxf(x, -30.f), 30.f);
  return 1.f / (1.f + __expf(-x));
}
__device__ __forceinline__ float tanh_(float x) {
  x = fminf(fmaxf(x, -15.f), 15.f);
  float e = __expf(2.f * x);
  return (e - 1.f) / (e + 1.f);
}

// lgkm-only block barrier (no vmcnt drain: out/EX stores stay in flight)
__device__ __forceinline__ void barrier_lgkm() {
  asm volatile("s_waitcnt lgkmcnt(0)" ::: "memory");
  __builtin_amdgcn_s_barrier();
}

__device__ __forceinline__ ull exload(const ull* p) {
  return __hip_atomic_load(p, __ATOMIC_RELAXED, __HIP_MEMORY_SCOPE_AGENT);
}

// ---------------- prep kernels ----------------

__global__ void k_prep_a(const float* __restrict__ x, ushort* __restrict__ a16, long nquad) {
  long i4 = (long)blockIdx.x * blockDim.x + threadIdx.x;
  if (i4 >= nquad) return;
  const float4 v = ((const float4*)x)[i4];
  ushort4 o;
  o.x = f2h(v.x); o.y = f2h(v.y); o.z = f2h(v.z); o.w = f2h(v.w);
  ((ushort4*)a16)[i4] = o;
}

__global__ void k_prep_w(const float* __restrict__ wf, const float* __restrict__ wb,
                         const float* __restrict__ bf1, const float* __restrict__ bf2,
                         const float* __restrict__ bb1, const float* __restrict__ bb2,
                         ushort* __restrict__ w16, float* __restrict__ biasc) {
  long i4 = (long)blockIdx.x * blockDim.x + threadIdx.x;
  if (i4 >= (long)NC * (KT / 4)) return;
  int n = (int)(i4 >> 7);
  int k4 = (int)(i4 & 127);
  int dir = n >> 10, g = n & 1023;
  const float* w = dir ? wb : wf;
  const float4 v = ((const float4*)(w + (size_t)g * Dn))[k4];
  ushort4 o;
  o.x = f2h(v.x); o.y = f2h(v.y); o.z = f2h(v.z); o.w = f2h(v.w);
  ((ushort4*)w16)[i4] = o;
  if (k4 == 0) biasc[n] = dir ? (bb1[g] + bb2[g]) : (bf1[g] + bf2[g]);
}

// Whh -> A-frags in per-(dir,half,wave) consumption order.
// frag = ((dir*2+half)*8 + w)*32 + p*4 + g ; phase p=0..7 (local kts first):
// ktphys = (p + 4*half) & 7 ; row = g*256 + half*128 + w*16 + (lane&15);
// k = ktphys*32 + (lane>>4)*8.
__global__ void k_prep_whh(const float* __restrict__ whhF, const float* __restrict__ whhB,
                           uint4* __restrict__ WF) {
  int t = blockIdx.x * blockDim.x + threadIdx.x;   // 0 .. 1024*64-1
  if (t >= 1024 * 64) return;
  int lane = t & 63;
  int frag = t >> 6;
  int g    = frag & 3;
  int p    = (frag >> 2) & 7;
  int w    = (frag >> 5) & 7;
  int half = (frag >> 8) & 1;
  int dir  = (frag >> 9) & 1;
  int row = g * 256 + half * 128 + w * 16 + (lane & 15);
  int ktphys = (p + 4 * half) & 7;
  int kb = ktphys * 32 + (lane >> 4) * 8;
  const float* whh = dir ? whhB : whhF;
  const float4* s = (const float4*)(whh + (size_t)row * Hn + kb);
  float4 v0 = s[0], v1 = s[1];
  WF[t] = (uint4){ packh(v0.x, v0.y), packh(v0.z, v0.w),
                   packh(v1.x, v1.y), packh(v1.z, v1.w) };
}

__global__ void k_bad(float* __restrict__ out, int n) {
  int i = blockIdx.x * blockDim.x + threadIdx.x;
  if (i < n) out[i] = 54321.f;
}

// ---------------- phase 1: fp16 MFMA GEMM (unchanged) ----------------

__device__ __forceinline__ void gload_lds16(const void* g, void* l) {
  __builtin_amdgcn_global_load_lds((const __attribute__((address_space(1))) void*)g,
                                   (__attribute__((address_space(3))) void*)l, 16, 0, 0);
}

__global__ __launch_bounds__(256) void k_gemm(const ushort* __restrict__ A,
                                              const ushort* __restrict__ W,
                                              const float* __restrict__ biasc,
                                              ushort* __restrict__ xp) {
  __shared__ __align__(16) ushort As[128 * 32];
  __shared__ __align__(16) ushort Bs[128 * 32];
  const int bid = blockIdx.x;
  const int m0 = (bid >> 4) * 128;
  const int n0 = (bid & 15) * 128;
  const int tid = threadIdx.x;
  const int wid = tid >> 6, lane = tid & 63;
  const int wr = wid >> 1, wcq = wid & 1;
  const int l16 = lane & 15, lq = lane >> 4;

  f32x4 acc[4][4] = {};

  for (int kt = 0; kt < KT; kt += 32) {
    __syncthreads();
#pragma unroll
    for (int i = 0; i < 2; ++i) {
      int ch = wid * 2 + i;
      int p = ch * 64 + lane;
      int r = p >> 2, gp = p & 3;
      int gs = gp ^ ((r >> 1) & 3);
      gload_lds16(A + (size_t)(m0 + r) * KT + kt + gs * 8, (char*)As + ch * 1024);
      gload_lds16(W + (size_t)(n0 + r) * KT + kt + gs * 8, (char*)Bs + ch * 1024);
    }
    __syncthreads();

    half8 af[4], bfr[4];
#pragma unroll
    for (int mfi = 0; mfi < 4; ++mfi) {
      int row = wr * 64 + mfi * 16 + l16;
      int g = lq ^ ((row >> 1) & 3);
      af[mfi] = *(const half8*)((const char*)As + row * 64 + g * 16);
    }
#pragma unroll
    for (int nf = 0; nf < 4; ++nf) {
      int row = wcq * 64 + nf * 16 + l16;
      int g = lq ^ ((row >> 1) & 3);
      bfr[nf] = *(const half8*)((const char*)Bs + row * 64 + g * 16);
    }
#pragma unroll
    for (int mfi = 0; mfi < 4; ++mfi)
#pragma unroll
      for (int nf = 0; nf < 4; ++nf)
        acc[mfi][nf] = __builtin_amdgcn_mfma_f32_16x16x32_f16(af[mfi], bfr[nf], acc[mfi][nf], 0, 0, 0);
  }

#pragma unroll
  for (int nf = 0; nf < 4; ++nf) {
    int col = n0 + wcq * 64 + nf * 16 + l16;
    float bv = biasc[col];
#pragma unroll
    for (int mfi = 0; mfi < 4; ++mfi) {
      int rbase = m0 + wr * 64 + mfi * 16 + lq * 4;
#pragma unroll
      for (int i = 0; i < 4; ++i)
        xp[(size_t)(rbase + i) * NC + col] = f2h(acc[mfi][nf][i] + bv);
    }
  }
}

// ---------------- phase 2: M-split recurrence, probe-ladder exchange ----------------
// bid = half*pairStride + p ; p = (bl<<1)|dir ; peer = bid ^ pairStride.
// EX[slot][bid][out]: {lo32: h fp32 bits, hi32: version}. Step t consumes version t
// from slot t&1 via probe ladder pv0 (prev tail, pre-stores) -> pv1 (step start) ->
// pv2 (mid phase-1) -> spin; posts version t+1 to slot (t+1)&1.

__global__ __launch_bounds__(512, 2) void k_lstm(const uint4* __restrict__ WF,
                                                 const ushort* __restrict__ xp,
                                                 float* __restrict__ out,
                                                 ull* __restrict__ EX,
                                                 int b_base, int pairStride) {
  const int bid  = blockIdx.x;
  const int half = (bid & pairStride) ? 1 : 0;
  const int p_   = bid & (pairStride - 1);
  const int dir  = p_ & 1;
  const int bl   = p_ >> 1;
  const int tid  = threadIdx.x;
  const int w    = tid >> 6;
  const int lane = tid & 63;
  const int lq   = lane >> 4;
  const int n    = lane & 15;          // output within wave (4x lane-redundant)

  __shared__ ushort hp[2][256];        // full h (both halves), double-buffered
  __shared__ float  gbuf[8][4][16];    // gate bounce

  // ---- persistent weights: 32 frags, all registers, consumption order ----
  const uint4* wfb = WF + (size_t)(((dir * 2 + half) * 8 + w) * 32) * 64 + lane;
  uint4 wA[32];
#pragma unroll
  for (int f = 0; f < 32; ++f) wA[f] = wfb[(size_t)f * 64];

  if (tid < 256) { hp[0][tid] = 0; hp[1][tid] = 0; }
  float creg = 0.f;
  __syncthreads();

  const int dstep = dir ? -1 : 1;
  const int t0 = dir ? (Tn - 1) : 0;
  const ptrdiff_t xstr = (ptrdiff_t)dstep * NC;
  const ptrdiff_t ostr = (ptrdiff_t)dstep * 512;
  const ushort* px = xp + (size_t)(bl * Tn + t0) * NC + dir * 1024 + half * 128 + w * 16 + n;
  float* pout = out + (size_t)((b_base + bl) * Tn + t0) * 512 + dir * 256 + half * 128 + w * 16 + n;

  const size_t myoff   = (size_t)bid * 128 + w * 16 + n;            // post entry
  const size_t peeroff = (size_t)(bid ^ pairStride) * 128 + tid;    // poll entry (tid<128)
  ull* exw = EX + myoff;
  const ull* prd = EX + peeroff;
  const int rbase = (half ^ 1) * 128;                               // remote half in hp

  int cur = 0;
  ull pv0 = 0xffffffff00000000ull;
  if (tid < 128) pv0 = exload(prd);            // rung 0 for t=0 (slot 0)

#pragma unroll 1
  for (int t = 0; t < Tn; ++t) {
    // xp for this lane's 4 gates (consumed in tail; latency hidden)
    ushort xg0 = px[0], xg1 = px[256], xg2 = px[512], xg3 = px[768];
    px += xstr;

    const ull* pe = prd + (size_t)(t & 1) * NBmax * 128;
    ull pv1 = pv0, pv2 = pv0;
    if (tid < 128) pv1 = exload(pe);           // rung 1: step start

    f32x4 acc0 = {0.f,0.f,0.f,0.f}, acc1 = {0.f,0.f,0.f,0.f};
    f32x4 acc2 = {0.f,0.f,0.f,0.f}, acc3 = {0.f,0.f,0.f,0.f};

    // ---- phase 1: local kts (p=0..3); probes in flight; rung 2 mid-phase ----
    const char* hb = (const char*)hp[cur];
    const int kb0 = (4 * half) * 64;   // local kt byte base (wraps within 512)
#pragma unroll
    for (int p = 0; p < 4; ++p) {
      uint4 b = *(const uint4*)(hb + ((kb0 + p * 64) & 511) + lq * 16);
      acc0 = mf(wA[p * 4 + 0], b, acc0);
      acc1 = mf(wA[p * 4 + 1], b, acc1);
      acc2 = mf(wA[p * 4 + 2], b, acc2);
      acc3 = mf(wA[p * 4 + 3], b, acc3);
      if (p == 1 && tid < 128) pv2 = exload(pe);   // rung 2
    }

    if (tid < 128) {                   // resolve ladder: oldest rung first
      ull v = pv0;
      if ((uint)(v >> 32) != (uint)t) v = pv1;
      if ((uint)(v >> 32) != (uint)t) v = pv2;
      while ((uint)(v >> 32) != (uint)t)
        v = exload(pe);
      hp[cur][rbase + tid] = f2h(__builtin_bit_cast(float, (uint)v));
    }
    barrier_lgkm();                    // remote half of h_{t-1} now in hp[cur]

    // ---- phase 2: remote kts (p=4..7) ----
    const int kb1 = (4 * (half ^ 1)) * 64;
#pragma unroll
    for (int p = 0; p < 4; ++p) {
      uint4 b = *(const uint4*)(hb + ((kb1 + p * 64) & 511) + lq * 16);
      acc0 = mf(wA[16 + p * 4 + 0], b, acc0);
      acc1 = mf(wA[16 + p * 4 + 1], b, acc1);
      acc2 = mf(wA[16 + p * 4 + 2], b, acc2);
      acc3 = mf(wA[16 + p * 4 + 3], b, acc3);
    }

    // ---- tail: bounce, activate; rung-0 probe for t+1 BEFORE the stores ----
    if ((lane & 15) == 0) {
      *(f32x4*)&gbuf[w][0][lq * 4] = acc0;
      *(f32x4*)&gbuf[w][1][lq * 4] = acc1;
      *(f32x4*)&gbuf[w][2][lq * 4] = acc2;
      *(f32x4*)&gbuf[w][3][lq * 4] = acc3;
    }
    // in-wave LDS dependency (compiler inserts lgkmcnt)
    float gi = gbuf[w][0][n] + h2f(xg0);
    float gf = gbuf[w][1][n] + h2f(xg1);
    float gg = gbuf[w][2][n] + h2f(xg2);
    float go = gbuf[w][3][n] + h2f(xg3);
    float iv = sig_(gi), fv = sig_(gf), gv = tanh_(gg), ov = sig_(go);
    creg = fv * creg + iv * gv;
    float h = ov * tanh_(creg);

    const size_t so = (size_t)((t + 1) & 1) * NBmax * 128;
    if (tid < 128)
      pv0 = exload(prd + so);          // rung 0 for t+1: issued BEFORE the stores,
                                       // so in-order vmcnt retires it without
                                       // waiting the MALL store-acks below
    if (lane < 16) {
      ull pk = (ull)__builtin_bit_cast(uint, h) | ((ull)(uint)(t + 1) << 32);
      __hip_atomic_store(exw + so, pk, __ATOMIC_RELAXED, __HIP_MEMORY_SCOPE_AGENT);
      *pout = h;
      hp[cur ^ 1][half * 128 + w * 16 + n] = f2h(h);
    }
    pout += ostr;
    barrier_lgkm();                    // local half of h_t visible to all waves
    cur ^= 1;
  }
}

// ---------------- host ----------------

extern "C" void kernel_launch(void* const* d_in, const int* in_sizes, int n_in,
                              void* d_out, int out_size, void* d_ws, size_t ws_size,
                              hipStream_t stream) {
  const float* x     = (const float*)d_in[0];
  const float* Wih_f = (const float*)d_in[1];
  const float* Whh_f = (const float*)d_in[2];
  const float* bih_f = (const float*)d_in[3];
  const float* bhh_f = (const float*)d_in[4];
  const float* Wih_b = (const float*)d_in[5];
  const float* Whh_b = (const float*)d_in[6];
  const float* bib_b = (const float*)d_in[7];
  const float* bhh_b = (const float*)d_in[8];
  float* out = (float*)d_out;

  const size_t szW16  = (size_t)NC * KT * 2;            // 2 MiB
  const size_t szBias = (size_t)NC * 4;
  const size_t szWF   = (size_t)1024 * 64 * 16;         // 1 MiB frag buffer
  const size_t szEX   = (size_t)2 * NBmax * 128 * 8;    // 256 KiB exchange

  int c = 0;
  size_t szA16 = 0, szXp = 0;
  for (int cc = 1; cc <= 16; cc *= 2) {
    size_t a = (size_t)(Bn / cc) * Tn * KT * 2;
    size_t p = (size_t)(Bn / cc) * Tn * NC * 2;
    if (szW16 + szBias + szWF + szEX + a + p <= ws_size) { c = cc; szA16 = a; szXp = p; break; }
  }
  if (c == 0) {
    k_bad<<<(out_size + 255) / 256, 256, 0, stream>>>(out, out_size);
    return;
  }

  char* ws = (char*)d_ws;
  ushort* W16   = (ushort*)ws;
  float*  biasc = (float*)(ws + szW16);
  uint4*  WF    = (uint4*)(ws + szW16 + szBias);
  ull*    EX    = (ull*)(ws + szW16 + szBias + szWF);
  ushort* A16   = (ushort*)(ws + szW16 + szBias + szWF + szEX);
  ushort* xp    = (ushort*)(ws + szW16 + szBias + szWF + szEX + szA16);

  {
    long n4 = (long)NC * (KT / 4);
    k_prep_w<<<(int)((n4 + 255) / 256), 256, 0, stream>>>(Wih_f, Wih_b, bih_f, bhh_f,
                                                          bib_b, bhh_b, W16, biasc);
  }
  k_prep_whh<<<(1024 * 64) / 256, 256, 0, stream>>>(Whh_f, Whh_b, WF);

  const int sizeB = Bn / c;
  const int pairStride = 2 * sizeB;    // peers bid and bid^pairStride share an XCD
  for (int cb = 0; cb < c; ++cb) {
    const int b_base = cb * sizeB;
    {
      long nquad = (long)sizeB * Tn * KT / 4;
      k_prep_a<<<(int)((nquad + 255) / 256), 256, 0, stream>>>(
          x + (size_t)b_base * Tn * Dn, A16, nquad);
    }
    k_gemm<<<dim3(sizeB * 8 * 16), dim3(256), 0, stream>>>(A16, W16, biasc, xp);
    hipMemsetAsync(EX, 0, szEX, stream);
    k_lstm<<<dim3(4 * sizeB), dim3(512), 0, stream>>>(WF, xp, out, EX, b_base, pairStride);
  }
}

// Round 17
// 1431.502 us; speedup vs baseline: 2.0687x; 1.0415x over previous
//
#include <hip/hip_runtime.h>
#include <cstdint>
#include <cstddef>

// Bidirectional LSTM  B=32 T=1024 D=512 H=256 (torch gate order i,f,g,o), fp32 in/out.
//
// FINAL (reverted to Round-11 best: 1430us total, k_lstm 1355us).
// Phase 1: xp = x @ Wih^T + bias  (fp16 MFMA GEMM, xp fp16)
// Phase 2: MFMA recurrence, 2-way M-split. Physical bid = half*pairStride + p,
//   p = (bl<<1)|dir  ->  peer = bid ^ pairStride: with 128 blocks peers differ by 64
//   (== 0 mod 8) -> same XCD under round-robin dispatch -> exchange resolves in the
//   shared per-XCD path. (Heuristic: perf-only, not correctness.)
//   Block owns 512 gate rows = 128 outputs; 8 waves; all 32 A-frags/wave in REGISTERS.
//   Exchange: 8B atomic {h fp32, version}, parity double-buffered EX[2]; step t
//   consumes version t from slot t&1 (early-probed BEFORE phase-1 MFMAs, re-polled
//   after). Barriers lgkmcnt-only (out/EX stores never drained).
// Measured plateau: latency-bound on agent-scope visibility (~1300cy/step);
// five design families explored (R3-R16), all alternatives >= this.

typedef unsigned int   uint;
typedef unsigned short ushort;
typedef unsigned long long ull;

constexpr int Tn = 1024;
constexpr int Bn = 32;
constexpr int Dn = 512;
constexpr int Hn = 256;
constexpr int NC = 2048;          // 2 dirs * 4H
constexpr int KT = 512;           // K of the input projection
constexpr int NBmax = 128;        // max recurrence blocks (EX stride)

typedef _Float16 half8  __attribute__((ext_vector_type(8)));
typedef float    f32x4  __attribute__((ext_vector_type(4)));

__device__ __forceinline__ ushort f2h(float f) {
  _Float16 h = (_Float16)f;               // RNE
  return __builtin_bit_cast(ushort, h);
}
__device__ __forceinline__ float h2f(ushort s) {
  return (float)__builtin_bit_cast(_Float16, s);
}
__device__ __forceinline__ uint packh(float a, float b) {
  return (uint)f2h(a) | ((uint)f2h(b) << 16);
}
__device__ __forceinline__ f32x4 mf(uint4 a, uint4 b, f32x4 c) {
  return __builtin_amdgcn_mfma_f32_16x16x32_f16(
      __builtin_bit_cast(half8, a), __builtin_bit_cast(half8, b), c, 0, 0, 0);
}

__device__ __forceinline__ float sig_(float x) {
  x = fminf(fmaxf(x, -30.f), 30.f);
  return 1.f / (1.f + __expf(-x));
}
__device__ __forceinline__ float tanh_(float x) {
  x = fminf(fmaxf(x, -15.f), 15.f);
  float e = __expf(2.f * x);
  return (e - 1.f) / (e + 1.f);
}

// lgkm-only block barrier (no vmcnt drain: out/EX stores stay in flight)
__device__ __forceinline__ void barrier_lgkm() {
  asm volatile("s_waitcnt lgkmcnt(0)" ::: "memory");
  __builtin_amdgcn_s_barrier();
}

// ---------------- prep kernels ----------------

__global__ void k_prep_a(const float* __restrict__ x, ushort* __restrict__ a16, long nquad) {
  long i4 = (long)blockIdx.x * blockDim.x + threadIdx.x;
  if (i4 >= nquad) return;
  const float4 v = ((const float4*)x)[i4];
  ushort4 o;
  o.x = f2h(v.x); o.y = f2h(v.y); o.z = f2h(v.z); o.w = f2h(v.w);
  ((ushort4*)a16)[i4] = o;
}

__global__ void k_prep_w(const float* __restrict__ wf, const float* __restrict__ wb,
                         const float* __restrict__ bf1, const float* __restrict__ bf2,
                         const float* __restrict__ bb1, const float* __restrict__ bb2,
                         ushort* __restrict__ w16, float* __restrict__ biasc) {
  long i4 = (long)blockIdx.x * blockDim.x + threadIdx.x;
  if (i4 >= (long)NC * (KT / 4)) return;
  int n = (int)(i4 >> 7);
  int k4 = (int)(i4 & 127);
  int dir = n >> 10, g = n & 1023;
  const float* w = dir ? wb : wf;
  const float4 v = ((const float4*)(w + (size_t)g * Dn))[k4];
  ushort4 o;
  o.x = f2h(v.x); o.y = f2h(v.y); o.z = f2h(v.z); o.w = f2h(v.w);
  ((ushort4*)w16)[i4] = o;
  if (k4 == 0) biasc[n] = dir ? (bb1[g] + bb2[g]) : (bf1[g] + bf2[g]);
}

// Whh -> A-frags in per-(dir,half,wave) consumption order.
// frag = ((dir*2+half)*8 + w)*32 + p*4 + g ; phase p=0..7 (local kts first):
// ktphys = (p + 4*half) & 7 ; row = g*256 + half*128 + w*16 + (lane&15);
// k = ktphys*32 + (lane>>4)*8.
__global__ void k_prep_whh(const float* __restrict__ whhF, const float* __restrict__ whhB,
                           uint4* __restrict__ WF) {
  int t = blockIdx.x * blockDim.x + threadIdx.x;   // 0 .. 1024*64-1
  if (t >= 1024 * 64) return;
  int lane = t & 63;
  int frag = t >> 6;
  int g    = frag & 3;
  int p    = (frag >> 2) & 7;
  int w    = (frag >> 5) & 7;
  int half = (frag >> 8) & 1;
  int dir  = (frag >> 9) & 1;
  int row = g * 256 + half * 128 + w * 16 + (lane & 15);
  int ktphys = (p + 4 * half) & 7;
  int kb = ktphys * 32 + (lane >> 4) * 8;
  const float* whh = dir ? whhB : whhF;
  const float4* s = (const float4*)(whh + (size_t)row * Hn + kb);
  float4 v0 = s[0], v1 = s[1];
  WF[t] = (uint4){ packh(v0.x, v0.y), packh(v0.z, v0.w),
                   packh(v1.x, v1.y), packh(v1.z, v1.w) };
}

__global__ void k_bad(float* __restrict__ out, int n) {
  int i = blockIdx.x * blockDim.x + threadIdx.x;
  if (i < n) out[i] = 54321.f;
}

// ---------------- phase 1: fp16 MFMA GEMM ----------------

__device__ __forceinline__ void gload_lds16(const void* g, void* l) {
  __builtin_amdgcn_global_load_lds((const __attribute__((address_space(1))) void*)g,
                                   (__attribute__((address_space(3))) void*)l, 16, 0, 0);
}

__global__ __launch_bounds__(256) void k_gemm(const ushort* __restrict__ A,
                                              const ushort* __restrict__ W,
                                              const float* __restrict__ biasc,
                                              ushort* __restrict__ xp) {
  __shared__ __align__(16) ushort As[128 * 32];
  __shared__ __align__(16) ushort Bs[128 * 32];
  const int bid = blockIdx.x;
  const int m0 = (bid >> 4) * 128;
  const int n0 = (bid & 15) * 128;
  const int tid = threadIdx.x;
  const int wid = tid >> 6, lane = tid & 63;
  const int wr = wid >> 1, wcq = wid & 1;
  const int l16 = lane & 15, lq = lane >> 4;

  f32x4 acc[4][4] = {};

  for (int kt = 0; kt < KT; kt += 32) {
    __syncthreads();
#pragma unroll
    for (int i = 0; i < 2; ++i) {
      int ch = wid * 2 + i;
      int p = ch * 64 + lane;
      int r = p >> 2, gp = p & 3;
      int gs = gp ^ ((r >> 1) & 3);
      gload_lds16(A + (size_t)(m0 + r) * KT + kt + gs * 8, (char*)As + ch * 1024);
      gload_lds16(W + (size_t)(n0 + r) * KT + kt + gs * 8, (char*)Bs + ch * 1024);
    }
    __syncthreads();

    half8 af[4], bfr[4];
#pragma unroll
    for (int mfi = 0; mfi < 4; ++mfi) {
      int row = wr * 64 + mfi * 16 + l16;
      int g = lq ^ ((row >> 1) & 3);
      af[mfi] = *(const half8*)((const char*)As + row * 64 + g * 16);
    }
#pragma unroll
    for (int nf = 0; nf < 4; ++nf) {
      int row = wcq * 64 + nf * 16 + l16;
      int g = lq ^ ((row >> 1) & 3);
      bfr[nf] = *(const half8*)((const char*)Bs + row * 64 + g * 16);
    }
#pragma unroll
    for (int mfi = 0; mfi < 4; ++mfi)
#pragma unroll
      for (int nf = 0; nf < 4; ++nf)
        acc[mfi][nf] = __builtin_amdgcn_mfma_f32_16x16x32_f16(af[mfi], bfr[nf], acc[mfi][nf], 0, 0, 0);
  }

#pragma unroll
  for (int nf = 0; nf < 4; ++nf) {
    int col = n0 + wcq * 64 + nf * 16 + l16;
    float bv = biasc[col];
#pragma unroll
    for (int mfi = 0; mfi < 4; ++mfi) {
      int rbase = m0 + wr * 64 + mfi * 16 + lq * 4;
#pragma unroll
      for (int i = 0; i < 4; ++i)
        xp[(size_t)(rbase + i) * NC + col] = f2h(acc[mfi][nf][i] + bv);
    }
  }
}

// ---------------- phase 2: M-split MFMA recurrence, same-XCD pairing ----------------
// bid = half*pairStride + p ; p = (bl<<1)|dir ; peer = bid ^ pairStride.
// EX[slot][bid][out]: ull = {lo32: h fp32 bits, hi32: version}. Step t consumes
// version t from slot t&1 (early-probed); posts version t+1 to slot (t+1)&1.

__global__ __launch_bounds__(512, 2) void k_lstm(const uint4* __restrict__ WF,
                                                 const ushort* __restrict__ xp,
                                                 float* __restrict__ out,
                                                 ull* __restrict__ EX,
                                                 int b_base, int pairStride) {
  const int bid  = blockIdx.x;
  const int half = (bid & pairStride) ? 1 : 0;
  const int p_   = bid & (pairStride - 1);
  const int dir  = p_ & 1;
  const int bl   = p_ >> 1;
  const int tid  = threadIdx.x;
  const int w    = tid >> 6;
  const int lane = tid & 63;
  const int lq   = lane >> 4;
  const int n    = lane & 15;          // output within wave (4x lane-redundant)

  __shared__ ushort hp[2][256];        // full h (both halves), double-buffered
  __shared__ float  gbuf[8][4][16];    // gate bounce

  // ---- persistent weights: 32 frags, all registers, consumption order ----
  const uint4* wfb = WF + (size_t)(((dir * 2 + half) * 8 + w) * 32) * 64 + lane;
  uint4 wA[32];
#pragma unroll
  for (int f = 0; f < 32; ++f) wA[f] = wfb[(size_t)f * 64];

  if (tid < 256) { hp[0][tid] = 0; hp[1][tid] = 0; }
  float creg = 0.f;
  __syncthreads();

  const int dstep = dir ? -1 : 1;
  const int t0 = dir ? (Tn - 1) : 0;
  const ptrdiff_t xstr = (ptrdiff_t)dstep * NC;
  const ptrdiff_t ostr = (ptrdiff_t)dstep * 512;
  const ushort* px = xp + (size_t)(bl * Tn + t0) * NC + dir * 1024 + half * 128 + w * 16 + n;
  float* pout = out + (size_t)((b_base + bl) * Tn + t0) * 512 + dir * 256 + half * 128 + w * 16 + n;

  ull* exw = EX + (size_t)bid * 128 + w * 16 + n;                    // + slot*NBmax*128
  const ull* exr = EX + (size_t)(bid ^ pairStride) * 128 + tid;      // pollers (tid<128)
  const int rbase = (half ^ 1) * 128;                                // remote half in hp

  int cur = 0;

#pragma unroll 1
  for (int t = 0; t < Tn; ++t) {
    // xp for this lane's 4 gates (consumed in tail; latency hidden)
    ushort xg0 = px[0], xg1 = px[256], xg2 = px[512], xg3 = px[768];
    px += xstr;

    // early probe: issue peer load BEFORE phase-1 MFMAs (usually already posted)
    const ull* pe = exr + (size_t)(t & 1) * NBmax * 128;
    ull v0l = 0;
    if (tid < 128)
      v0l = __hip_atomic_load(pe, __ATOMIC_RELAXED, __HIP_MEMORY_SCOPE_AGENT);

    f32x4 acc0 = {0.f,0.f,0.f,0.f}, acc1 = {0.f,0.f,0.f,0.f};
    f32x4 acc2 = {0.f,0.f,0.f,0.f}, acc3 = {0.f,0.f,0.f,0.f};

    // ---- phase 1: local kts (p=0..3); probe latency hides under these ----
    const char* hb = (const char*)hp[cur];
    const int kb0 = (4 * half) * 64;   // local kt byte base (wraps within 512)
#pragma unroll
    for (int p = 0; p < 4; ++p) {
      uint4 b = *(const uint4*)(hb + ((kb0 + p * 64) & 511) + lq * 16);
      acc0 = mf(wA[p * 4 + 0], b, acc0);
      acc1 = mf(wA[p * 4 + 1], b, acc1);
      acc2 = mf(wA[p * 4 + 2], b, acc2);
      acc3 = mf(wA[p * 4 + 3], b, acc3);
    }

    if (tid < 128) {                   // finish poll (spin only if probe was stale)
      ull v = v0l;
      while ((uint)(v >> 32) != (uint)t)
        v = __hip_atomic_load(pe, __ATOMIC_RELAXED, __HIP_MEMORY_SCOPE_AGENT);
      hp[cur][rbase + tid] = f2h(__builtin_bit_cast(float, (uint)v));
    }
    barrier_lgkm();                    // remote half of h_{t-1} now in hp[cur]

    // ---- phase 2: remote kts (p=4..7) ----
    const int kb1 = (4 * (half ^ 1)) * 64;
#pragma unroll
    for (int p = 0; p < 4; ++p) {
      uint4 b = *(const uint4*)(hb + ((kb1 + p * 64) & 511) + lq * 16);
      acc0 = mf(wA[16 + p * 4 + 0], b, acc0);
      acc1 = mf(wA[16 + p * 4 + 1], b, acc1);
      acc2 = mf(wA[16 + p * 4 + 2], b, acc2);
      acc3 = mf(wA[16 + p * 4 + 3], b, acc3);
    }

    // ---- tail: bounce D col0 rows, activate, post h (EX first) ----
    if ((lane & 15) == 0) {
      *(f32x4*)&gbuf[w][0][lq * 4] = acc0;
      *(f32x4*)&gbuf[w][1][lq * 4] = acc1;
      *(f32x4*)&gbuf[w][2][lq * 4] = acc2;
      *(f32x4*)&gbuf[w][3][lq * 4] = acc3;
    }
    // in-wave LDS dependency (compiler inserts lgkmcnt)
    float gi = gbuf[w][0][n] + h2f(xg0);
    float gf = gbuf[w][1][n] + h2f(xg1);
    float gg = gbuf[w][2][n] + h2f(xg2);
    float go = gbuf[w][3][n] + h2f(xg3);
    float iv = sig_(gi), fv = sig_(gf), gv = tanh_(gg), ov = sig_(go);
    creg = fv * creg + iv * gv;
    float h = ov * tanh_(creg);
    if (lane < 16) {
      ull pk = (ull)__builtin_bit_cast(uint, h) | ((ull)(uint)(t + 1) << 32);
      __hip_atomic_store(exw + (size_t)((t + 1) & 1) * NBmax * 128, pk,
                         __ATOMIC_RELAXED, __HIP_MEMORY_SCOPE_AGENT);
      *pout = h;
      hp[cur ^ 1][half * 128 + w * 16 + n] = f2h(h);
    }
    pout += ostr;
    barrier_lgkm();                    // local half of h_t visible to all waves
    cur ^= 1;
  }
}

// ---------------- host ----------------

extern "C" void kernel_launch(void* const* d_in, const int* in_sizes, int n_in,
                              void* d_out, int out_size, void* d_ws, size_t ws_size,
                              hipStream_t stream) {
  const float* x     = (const float*)d_in[0];
  const float* Wih_f = (const float*)d_in[1];
  const float* Whh_f = (const float*)d_in[2];
  const float* bih_f = (const float*)d_in[3];
  const float* bhh_f = (const float*)d_in[4];
  const float* Wih_b = (const float*)d_in[5];
  const float* Whh_b = (const float*)d_in[6];
  const float* bib_b = (const float*)d_in[7];
  const float* bhh_b = (const float*)d_in[8];
  float* out = (float*)d_out;

  const size_t szW16  = (size_t)NC * KT * 2;            // 2 MiB
  const size_t szBias = (size_t)NC * 4;
  const size_t szWF   = (size_t)1024 * 64 * 16;         // 1 MiB frag buffer
  const size_t szEX   = (size_t)2 * NBmax * 128 * 8;    // 256 KiB exchange

  int c = 0;
  size_t szA16 = 0, szXp = 0;
  for (int cc = 1; cc <= 16; cc *= 2) {
    size_t a = (size_t)(Bn / cc) * Tn * KT * 2;
    size_t p = (size_t)(Bn / cc) * Tn * NC * 2;
    if (szW16 + szBias + szWF + szEX + a + p <= ws_size) { c = cc; szA16 = a; szXp = p; break; }
  }
  if (c == 0) {
    k_bad<<<(out_size + 255) / 256, 256, 0, stream>>>(out, out_size);
    return;
  }

  char* ws = (char*)d_ws;
  ushort* W16   = (ushort*)ws;
  float*  biasc = (float*)(ws + szW16);
  uint4*  WF    = (uint4*)(ws + szW16 + szBias);
  ull*    EX    = (ull*)(ws + szW16 + szBias + szWF);
  ushort* A16   = (ushort*)(ws + szW16 + szBias + szWF + szEX);
  ushort* xp    = (ushort*)(ws + szW16 + szBias + szWF + szEX + szA16);

  {
    long n4 = (long)NC * (KT / 4);
    k_prep_w<<<(int)((n4 + 255) / 256), 256, 0, stream>>>(Wih_f, Wih_b, bih_f, bhh_f,
                                                          bib_b, bhh_b, W16, biasc);
  }
  k_prep_whh<<<(1024 * 64) / 256, 256, 0, stream>>>(Whh_f, Whh_b, WF);

  const int sizeB = Bn / c;
  const int pairStride = 2 * sizeB;    // peers bid and bid^pairStride share an XCD
  for (int cb = 0; cb < c; ++cb) {
    const int b_base = cb * sizeB;
    {
      long nquad = (long)sizeB * Tn * KT / 4;
      k_prep_a<<<(int)((nquad + 255) / 256), 256, 0, stream>>>(
          x + (size_t)b_base * Tn * Dn, A16, nquad);
    }
    k_gemm<<<dim3(sizeB * 8 * 16), dim3(256), 0, stream>>>(A16, W16, biasc, xp);
    hipMemsetAsync(EX, 0, szEX, stream);
    k_lstm<<<dim3(4 * sizeB), dim3(512), 0, stream>>>(WF, xp, out, EX, b_base, pairStride);
  }
}

// Round 18
// 1307.194 us; speedup vs baseline: 2.2654x; 1.0951x over previous
//
#include <hip/hip_runtime.h>
#include <cstdint>
#include <cstddef>

// Bidirectional LSTM  B=32 T=1024 D=512 H=256 (torch gate order i,f,g,o), fp32 in/out.
//
// Phase 1: xp = x @ Wih^T + bias  (fp16 MFMA GEMM, xp fp16)
// Phase 2: ZERO-COMMUNICATION i8 MFMA recurrence. One block per (dir,batch) chain
//   (64 blocks, 512 thr, 8 waves; wave w owns outputs [32w,32w+32), M-tiles
//   {g*16+2w+j}). Whh quantized per-row to int8 (s=rowmax/127): ALL 32 A-frags/wave
//   (mfma_i32_16x16x64_i8, K=64, 4 regs each) = 128 VGPRs -> no LDS/L2/HBM weight
//   traffic, no cross-CU exchange, no MALL latency. h re-quantized to i8 (x127)
//   each step into a 512B parity-buffered LDS array. Gates: i32 acc x fp32 per-row
//   scale + fp16 xp. 256 i8-MFMA/CU/step ~= 1300cy pipe floor. 1 lgkm barrier/step.

typedef unsigned int   uint;
typedef unsigned short ushort;

constexpr int Tn = 1024;
constexpr int Bn = 32;
constexpr int Dn = 512;
constexpr int Hn = 256;
constexpr int NC = 2048;          // 2 dirs * 4H
constexpr int KT = 512;           // K of the input projection

typedef _Float16 half8  __attribute__((ext_vector_type(8)));
typedef float    f32x4  __attribute__((ext_vector_type(4)));
typedef int      i32x4  __attribute__((ext_vector_type(4)));

__device__ __forceinline__ ushort f2h(float f) {
  _Float16 h = (_Float16)f;               // RNE
  return __builtin_bit_cast(ushort, h);
}
__device__ __forceinline__ float h2f(ushort s) {
  return (float)__builtin_bit_cast(_Float16, s);
}
__device__ __forceinline__ uint packh(float a, float b) {
  return (uint)f2h(a) | ((uint)f2h(b) << 16);
}
__device__ __forceinline__ f32x4 mf(uint4 a, uint4 b, f32x4 c) {
  return __builtin_amdgcn_mfma_f32_16x16x32_f16(
      __builtin_bit_cast(half8, a), __builtin_bit_cast(half8, b), c, 0, 0, 0);
}
__device__ __forceinline__ i32x4 mfi8(uint4 a, uint4 b, i32x4 c) {
  return __builtin_amdgcn_mfma_i32_16x16x64_i8(
      __builtin_bit_cast(i32x4, a), __builtin_bit_cast(i32x4, b), c, 0, 0, 0);
}

__device__ __forceinline__ float sig_(float x) {
  x = fminf(fmaxf(x, -30.f), 30.f);
  return 1.f / (1.f + __expf(-x));
}
__device__ __forceinline__ float tanh_(float x) {
  x = fminf(fmaxf(x, -15.f), 15.f);
  float e = __expf(2.f * x);
  return (e - 1.f) / (e + 1.f);
}

// lgkm-only block barrier (no vmcnt drain: out-stores stay in flight)
__device__ __forceinline__ void barrier_lgkm() {
  asm volatile("s_waitcnt lgkmcnt(0)" ::: "memory");
  __builtin_amdgcn_s_barrier();
}

// ---------------- prep kernels ----------------

__global__ void k_prep_a(const float* __restrict__ x, ushort* __restrict__ a16, long nquad) {
  long i4 = (long)blockIdx.x * blockDim.x + threadIdx.x;
  if (i4 >= nquad) return;
  const float4 v = ((const float4*)x)[i4];
  ushort4 o;
  o.x = f2h(v.x); o.y = f2h(v.y); o.z = f2h(v.z); o.w = f2h(v.w);
  ((ushort4*)a16)[i4] = o;
}

__global__ void k_prep_w(const float* __restrict__ wf, const float* __restrict__ wb,
                         const float* __restrict__ bf1, const float* __restrict__ bf2,
                         const float* __restrict__ bb1, const float* __restrict__ bb2,
                         ushort* __restrict__ w16, float* __restrict__ biasc) {
  long i4 = (long)blockIdx.x * blockDim.x + threadIdx.x;
  if (i4 >= (long)NC * (KT / 4)) return;
  int n = (int)(i4 >> 7);
  int k4 = (int)(i4 & 127);
  int dir = n >> 10, g = n & 1023;
  const float* w = dir ? wb : wf;
  const float4 v = ((const float4*)(w + (size_t)g * Dn))[k4];
  ushort4 o;
  o.x = f2h(v.x); o.y = f2h(v.y); o.z = f2h(v.z); o.w = f2h(v.w);
  ((ushort4*)w16)[i4] = o;
  if (k4 == 0) biasc[n] = dir ? (bb1[g] + bb2[g]) : (bf1[g] + bf2[g]);
}

// per-row quant scale: sq[dir*1024+row] = rowmax/127
__global__ void k_scale(const float* __restrict__ whhF, const float* __restrict__ whhB,
                        float* __restrict__ sq) {
  int t = blockIdx.x * blockDim.x + threadIdx.x;
  if (t >= 2048) return;
  int dir = t >> 10, row = t & 1023;
  const float* w = (dir ? whhB : whhF) + (size_t)row * Hn;
  float m = 0.f;
  for (int i = 0; i < Hn; ++i) m = fmaxf(m, fabsf(w[i]));
  sq[t] = fmaxf(m, 1e-30f) / 127.f;
}

// Whh -> i8 A-frags. WF8[dir][w][frag=kt*8+m][lane] (uint4 = 16 x i8).
// m: g=m>>1, j=m&1; row = (g*16+2w+j)*16 + (lane&15); k = kt*64 + (lane>>4)*16 + 0..15.
__global__ void k_prep_whh8(const float* __restrict__ whhF, const float* __restrict__ whhB,
                            const float* __restrict__ sq, uint4* __restrict__ WF8) {
  int t = blockIdx.x * blockDim.x + threadIdx.x;   // 0 .. 32767
  if (t >= 2 * 8 * 32 * 64) return;
  int lane = t & 63;
  int frag = (t >> 6) & 31;
  int w    = (t >> 11) & 7;
  int dir  = (t >> 14) & 1;
  int m  = frag & 7, kt = frag >> 3;
  int g = m >> 1, j = m & 1;
  int row = (g * 16 + 2 * w + j) * 16 + (lane & 15);
  int kb  = kt * 64 + (lane >> 4) * 16;
  const float* whh = dir ? whhB : whhF;
  const float* src = whh + (size_t)row * Hn + kb;
  float inv = 1.f / sq[dir * 1024 + row];          // = 127/rowmax
  uint pk[4];
#pragma unroll
  for (int q = 0; q < 4; ++q) {
    uint v = 0;
#pragma unroll
    for (int b = 0; b < 4; ++b) {
      float f = src[q * 4 + b] * inv;
      int iq = (int)rintf(fminf(fmaxf(f, -127.f), 127.f));
      v |= ((uint)(unsigned char)(signed char)iq) << (8 * b);
    }
    pk[q] = v;
  }
  WF8[t] = (uint4){pk[0], pk[1], pk[2], pk[3]};
}

__global__ void k_bad(float* __restrict__ out, int n) {
  int i = blockIdx.x * blockDim.x + threadIdx.x;
  if (i < n) out[i] = 54321.f;
}

// ---------------- phase 1: fp16 MFMA GEMM (unchanged) ----------------

__device__ __forceinline__ void gload_lds16(const void* g, void* l) {
  __builtin_amdgcn_global_load_lds((const __attribute__((address_space(1))) void*)g,
                                   (__attribute__((address_space(3))) void*)l, 16, 0, 0);
}

__global__ __launch_bounds__(256) void k_gemm(const ushort* __restrict__ A,
                                              const ushort* __restrict__ W,
                                              const float* __restrict__ biasc,
                                              ushort* __restrict__ xp) {
  __shared__ __align__(16) ushort As[128 * 32];
  __shared__ __align__(16) ushort Bs[128 * 32];
  const int bid = blockIdx.x;
  const int m0 = (bid >> 4) * 128;
  const int n0 = (bid & 15) * 128;
  const int tid = threadIdx.x;
  const int wid = tid >> 6, lane = tid & 63;
  const int wr = wid >> 1, wcq = wid & 1;
  const int l16 = lane & 15, lq = lane >> 4;

  f32x4 acc[4][4] = {};

  for (int kt = 0; kt < KT; kt += 32) {
    __syncthreads();
#pragma unroll
    for (int i = 0; i < 2; ++i) {
      int ch = wid * 2 + i;
      int p = ch * 64 + lane;
      int r = p >> 2, gp = p & 3;
      int gs = gp ^ ((r >> 1) & 3);
      gload_lds16(A + (size_t)(m0 + r) * KT + kt + gs * 8, (char*)As + ch * 1024);
      gload_lds16(W + (size_t)(n0 + r) * KT + kt + gs * 8, (char*)Bs + ch * 1024);
    }
    __syncthreads();

    half8 af[4], bfr[4];
#pragma unroll
    for (int mfi = 0; mfi < 4; ++mfi) {
      int row = wr * 64 + mfi * 16 + l16;
      int g = lq ^ ((row >> 1) & 3);
      af[mfi] = *(const half8*)((const char*)As + row * 64 + g * 16);
    }
#pragma unroll
    for (int nf = 0; nf < 4; ++nf) {
      int row = wcq * 64 + nf * 16 + l16;
      int g = lq ^ ((row >> 1) & 3);
      bfr[nf] = *(const half8*)((const char*)Bs + row * 64 + g * 16);
    }
#pragma unroll
    for (int mfi = 0; mfi < 4; ++mfi)
#pragma unroll
      for (int nf = 0; nf < 4; ++nf)
        acc[mfi][nf] = __builtin_amdgcn_mfma_f32_16x16x32_f16(af[mfi], bfr[nf], acc[mfi][nf], 0, 0, 0);
  }

#pragma unroll
  for (int nf = 0; nf < 4; ++nf) {
    int col = n0 + wcq * 64 + nf * 16 + l16;
    float bv = biasc[col];
#pragma unroll
    for (int mfi = 0; mfi < 4; ++mfi) {
      int rbase = m0 + wr * 64 + mfi * 16 + lq * 4;
#pragma unroll
      for (int i = 0; i < 4; ++i)
        xp[(size_t)(rbase + i) * NC + col] = f2h(acc[mfi][nf][i] + bv);
    }
  }
}

// ---------------- phase 2: zero-comm i8 MFMA recurrence ----------------
// bid: dir = &1, bl = >>1. Wave w owns outputs 32w..32w+31 (tiles g*16+2w+j).
// acc[m] over kt=0..3; bounce i32 acc through per-wave gbuf; gates = acc*fdq + xp.

__global__ __launch_bounds__(512, 2) void k_lstm(const uint4* __restrict__ WF8,
                                                 const float* __restrict__ sq,
                                                 const ushort* __restrict__ xp,
                                                 float* __restrict__ out,
                                                 int b_base) {
  const int dir = blockIdx.x & 1;
  const int bl  = blockIdx.x >> 1;
  const int tid = threadIdx.x;
  const int w    = tid >> 6;
  const int lane = tid & 63;
  const int lq   = lane >> 4;
  const int n    = lane & 31;          // this lane's output (2x redundant)

  __shared__ __align__(16) char hq[2][256];    // i8 h, parity double-buffered
  __shared__ __align__(16) int  gbuf[8][128];  // i32 gate bounce, per-wave

  // ---- persistent weights: all 32 i8 frags in registers (128 VGPRs) ----
  const uint4* wfb = WF8 + (size_t)((dir * 8 + w) * 32) * 64 + lane;
  uint4 wA[32];
#pragma unroll
  for (int f = 0; f < 32; ++f) wA[f] = wfb[(size_t)f * 64];

  // per-output dequant scales (4 gate rows), includes the 1/127 h-scale
  float fdq[4];
#pragma unroll
  for (int g = 0; g < 4; ++g)
    fdq[g] = sq[dir * 1024 + g * 256 + 32 * w + n] * (1.f / 127.f);

  if (tid < 128) ((uint*)hq)[tid] = 0;         // h_{-1} = 0 (both buffers)
  float creg = 0.f;
  __syncthreads();

  const int dstep = dir ? -1 : 1;
  const int t0 = dir ? (Tn - 1) : 0;
  const ptrdiff_t xstr = (ptrdiff_t)dstep * NC;
  const ptrdiff_t ostr = (ptrdiff_t)dstep * 512;
  const ushort* px = xp + (size_t)(bl * Tn + t0) * NC + dir * 1024 + 32 * w + n;
  float* pout = out + (size_t)((b_base + bl) * Tn + t0) * 512 + dir * 256 + 32 * w + n;

  int cur = 0;
#pragma unroll 1
  for (int t = 0; t < Tn; ++t) {
    // xp for this lane's 4 gates (consumed in tail; latency hidden under MFMA)
    ushort xg0 = px[0], xg1 = px[256], xg2 = px[512], xg3 = px[768];
    px += xstr;

    // B-frags: 16 i8 h-values per kt (uniform per lane-quad; all 16 cols equal)
    uint4 bq[4];
#pragma unroll
    for (int kt = 0; kt < 4; ++kt)
      bq[kt] = *(const uint4*)(hq[cur] + kt * 64 + lq * 16);

    i32x4 acc[8];
#pragma unroll
    for (int m = 0; m < 8; ++m) acc[m] = (i32x4){0, 0, 0, 0};
#pragma unroll
    for (int kt = 0; kt < 4; ++kt)
#pragma unroll
      for (int m = 0; m < 8; ++m)
        acc[m] = mfi8(wA[kt * 8 + m], bq[kt], acc[m]);

    // bounce D col-0 rows (i32) through per-wave gbuf; same-wave LDS dep
    if ((lane & 15) == 0) {
#pragma unroll
      for (int m = 0; m < 8; ++m)
        *(i32x4*)&gbuf[w][(m >> 1) * 32 + (m & 1) * 16 + lq * 4] = acc[m];
    }
    float gi = (float)gbuf[w][0 * 32 + n] * fdq[0] + h2f(xg0);
    float gf = (float)gbuf[w][1 * 32 + n] * fdq[1] + h2f(xg1);
    float gg = (float)gbuf[w][2 * 32 + n] * fdq[2] + h2f(xg2);
    float go = (float)gbuf[w][3 * 32 + n] * fdq[3] + h2f(xg3);
    float iv = sig_(gi), fv = sig_(gf), gv = tanh_(gg), ov = sig_(go);
    creg = fv * creg + iv * gv;
    float h = ov * tanh_(creg);
    if (lane < 32) {
      *pout = h;                                   // fp32 output (drains lazily)
      int q = (int)rintf(h * 127.f);               // |h|<1 -> q in [-127,127]
      hq[cur ^ 1][32 * w + n] = (char)q;           // i8 h for next step
    }
    pout += ostr;
    barrier_lgkm();                                // h_t visible to all waves
    cur ^= 1;
  }
}

// ---------------- host ----------------

extern "C" void kernel_launch(void* const* d_in, const int* in_sizes, int n_in,
                              void* d_out, int out_size, void* d_ws, size_t ws_size,
                              hipStream_t stream) {
  const float* x     = (const float*)d_in[0];
  const float* Wih_f = (const float*)d_in[1];
  const float* Whh_f = (const float*)d_in[2];
  const float* bih_f = (const float*)d_in[3];
  const float* bhh_f = (const float*)d_in[4];
  const float* Wih_b = (const float*)d_in[5];
  const float* Whh_b = (const float*)d_in[6];
  const float* bib_b = (const float*)d_in[7];
  const float* bhh_b = (const float*)d_in[8];
  float* out = (float*)d_out;

  const size_t szW16  = (size_t)NC * KT * 2;            // 2 MiB
  const size_t szBias = (size_t)NC * 4;
  const size_t szSq   = 2048 * 4;                       // 8 KiB row scales
  const size_t szWF8  = (size_t)2 * 8 * 32 * 64 * 16;   // 512 KiB i8 frag buffer

  int c = 0;
  size_t szA16 = 0, szXp = 0;
  for (int cc = 1; cc <= 16; cc *= 2) {
    size_t a = (size_t)(Bn / cc) * Tn * KT * 2;
    size_t p = (size_t)(Bn / cc) * Tn * NC * 2;
    if (szW16 + szBias + szSq + szWF8 + a + p <= ws_size) { c = cc; szA16 = a; szXp = p; break; }
  }
  if (c == 0) {
    k_bad<<<(out_size + 255) / 256, 256, 0, stream>>>(out, out_size);
    return;
  }

  char* ws = (char*)d_ws;
  ushort* W16   = (ushort*)ws;
  float*  biasc = (float*)(ws + szW16);
  float*  sq    = (float*)(ws + szW16 + szBias);
  uint4*  WF8   = (uint4*)(ws + szW16 + szBias + szSq);
  ushort* A16   = (ushort*)(ws + szW16 + szBias + szSq + szWF8);
  ushort* xp    = (ushort*)(ws + szW16 + szBias + szSq + szWF8 + szA16);

  {
    long n4 = (long)NC * (KT / 4);
    k_prep_w<<<(int)((n4 + 255) / 256), 256, 0, stream>>>(Wih_f, Wih_b, bih_f, bhh_f,
                                                          bib_b, bhh_b, W16, biasc);
  }
  k_scale<<<8, 256, 0, stream>>>(Whh_f, Whh_b, sq);
  k_prep_whh8<<<(2 * 8 * 32 * 64) / 256, 256, 0, stream>>>(Whh_f, Whh_b, sq, WF8);

  const int sizeB = Bn / c;
  for (int cb = 0; cb < c; ++cb) {
    const int b_base = cb * sizeB;
    {
      long nquad = (long)sizeB * Tn * KT / 4;
      k_prep_a<<<(int)((nquad + 255) / 256), 256, 0, stream>>>(
          x + (size_t)b_base * Tn * Dn, A16, nquad);
    }
    k_gemm<<<dim3(sizeB * 8 * 16), dim3(256), 0, stream>>>(A16, W16, biasc, xp);
    k_lstm<<<dim3(2 * sizeB), dim3(512), 0, stream>>>(WF8, sq, xp, out, b_base);
  }
}

// Round 19
// 1278.591 us; speedup vs baseline: 2.3161x; 1.0224x over previous
//
#include <hip/hip_runtime.h>
#include <cstdint>
#include <cstddef>

// Bidirectional LSTM  B=32 T=1024 D=512 H=256 (torch gate order i,f,g,o), fp32 in/out.
//
// Phase 1: xp = x @ Wih^T + bias  (fp16 MFMA GEMM, xp fp16)
// Phase 2: ZERO-COMMUNICATION i8 MFMA recurrence (R18 structure) + step-path cuts:
//   (1) xp prefetched one FULL step ahead (converted to fp32 during MFMA phase) --
//       tail consumes registers only, no exposed global latency;
//   (2) j=0 gate-bounce written right after its 4 chains finish, hiding under the
//       j=1 MFMAs (gbuf read indices unchanged: slot = g*32 + n);
//   (3) activation via v_rcp_f32 (sig = rcp(1+e^-x), tanh = 1-2*rcp(e^2x+1)),
//       clamps dropped (rcp(inf)=0 gives exact saturation), err ~1e-5 << budget.
//   One block per (dir,batch) chain; all 32 i8 A-frags (mfma_i32_16x16x64_i8) in
//   registers; h re-quantized to i8 each step; 1 lgkm barrier/step.

typedef unsigned int   uint;
typedef unsigned short ushort;

constexpr int Tn = 1024;
constexpr int Bn = 32;
constexpr int Dn = 512;
constexpr int Hn = 256;
constexpr int NC = 2048;          // 2 dirs * 4H
constexpr int KT = 512;           // K of the input projection

typedef _Float16 half8  __attribute__((ext_vector_type(8)));
typedef float    f32x4  __attribute__((ext_vector_type(4)));
typedef int      i32x4  __attribute__((ext_vector_type(4)));

__device__ __forceinline__ ushort f2h(float f) {
  _Float16 h = (_Float16)f;               // RNE
  return __builtin_bit_cast(ushort, h);
}
__device__ __forceinline__ float h2f(ushort s) {
  return (float)__builtin_bit_cast(_Float16, s);
}
__device__ __forceinline__ uint packh(float a, float b) {
  return (uint)f2h(a) | ((uint)f2h(b) << 16);
}
__device__ __forceinline__ f32x4 mf(uint4 a, uint4 b, f32x4 c) {
  return __builtin_amdgcn_mfma_f32_16x16x32_f16(
      __builtin_bit_cast(half8, a), __builtin_bit_cast(half8, b), c, 0, 0, 0);
}
__device__ __forceinline__ i32x4 mfi8(uint4 a, uint4 b, i32x4 c) {
  return __builtin_amdgcn_mfma_i32_16x16x64_i8(
      __builtin_bit_cast(i32x4, a), __builtin_bit_cast(i32x4, b), c, 0, 0, 0);
}

#if defined(__has_builtin)
#  if __has_builtin(__builtin_amdgcn_rcpf)
#    define RCPF(x) __builtin_amdgcn_rcpf(x)
#  endif
#endif
#ifndef RCPF
#  define RCPF(x) (1.f / (x))
#endif

__device__ __forceinline__ float sigr_(float x) {      // rcp handles saturation
  return RCPF(1.f + __expf(-x));
}
__device__ __forceinline__ float tanhr_(float x) {
  float e = __expf(2.f * x);
  return fmaf(-2.f, RCPF(e + 1.f), 1.f);
}
__device__ __forceinline__ float sig_(float x) {       // used only by ref paths
  x = fminf(fmaxf(x, -30.f), 30.f);
  return 1.f / (1.f + __expf(-x));
}

// lgkm-only block barrier (no vmcnt drain: out-stores stay in flight)
__device__ __forceinline__ void barrier_lgkm() {
  asm volatile("s_waitcnt lgkmcnt(0)" ::: "memory");
  __builtin_amdgcn_s_barrier();
}

// ---------------- prep kernels ----------------

__global__ void k_prep_a(const float* __restrict__ x, ushort* __restrict__ a16, long nquad) {
  long i4 = (long)blockIdx.x * blockDim.x + threadIdx.x;
  if (i4 >= nquad) return;
  const float4 v = ((const float4*)x)[i4];
  ushort4 o;
  o.x = f2h(v.x); o.y = f2h(v.y); o.z = f2h(v.z); o.w = f2h(v.w);
  ((ushort4*)a16)[i4] = o;
}

__global__ void k_prep_w(const float* __restrict__ wf, const float* __restrict__ wb,
                         const float* __restrict__ bf1, const float* __restrict__ bf2,
                         const float* __restrict__ bb1, const float* __restrict__ bb2,
                         ushort* __restrict__ w16, float* __restrict__ biasc) {
  long i4 = (long)blockIdx.x * blockDim.x + threadIdx.x;
  if (i4 >= (long)NC * (KT / 4)) return;
  int n = (int)(i4 >> 7);
  int k4 = (int)(i4 & 127);
  int dir = n >> 10, g = n & 1023;
  const float* w = dir ? wb : wf;
  const float4 v = ((const float4*)(w + (size_t)g * Dn))[k4];
  ushort4 o;
  o.x = f2h(v.x); o.y = f2h(v.y); o.z = f2h(v.z); o.w = f2h(v.w);
  ((ushort4*)w16)[i4] = o;
  if (k4 == 0) biasc[n] = dir ? (bb1[g] + bb2[g]) : (bf1[g] + bf2[g]);
}

// per-row quant scale: sq[dir*1024+row] = rowmax/127
__global__ void k_scale(const float* __restrict__ whhF, const float* __restrict__ whhB,
                        float* __restrict__ sq) {
  int t = blockIdx.x * blockDim.x + threadIdx.x;
  if (t >= 2048) return;
  int dir = t >> 10, row = t & 1023;
  const float* w = (dir ? whhB : whhF) + (size_t)row * Hn;
  float m = 0.f;
  for (int i = 0; i < Hn; ++i) m = fmaxf(m, fabsf(w[i]));
  sq[t] = fmaxf(m, 1e-30f) / 127.f;
}

// Whh -> i8 A-frags. WF8[dir][w][frag=kt*8+m][lane] (uint4 = 16 x i8).
// m: g=m>>1, j=m&1; row = (g*16+2w+j)*16 + (lane&15); k = kt*64 + (lane>>4)*16 + 0..15.
__global__ void k_prep_whh8(const float* __restrict__ whhF, const float* __restrict__ whhB,
                            const float* __restrict__ sq, uint4* __restrict__ WF8) {
  int t = blockIdx.x * blockDim.x + threadIdx.x;   // 0 .. 32767
  if (t >= 2 * 8 * 32 * 64) return;
  int lane = t & 63;
  int frag = (t >> 6) & 31;
  int w    = (t >> 11) & 7;
  int dir  = (t >> 14) & 1;
  int m  = frag & 7, kt = frag >> 3;
  int g = m >> 1, j = m & 1;
  int row = (g * 16 + 2 * w + j) * 16 + (lane & 15);
  int kb  = kt * 64 + (lane >> 4) * 16;
  const float* whh = dir ? whhB : whhF;
  const float* src = whh + (size_t)row * Hn + kb;
  float inv = 1.f / sq[dir * 1024 + row];          // = 127/rowmax
  uint pk[4];
#pragma unroll
  for (int q = 0; q < 4; ++q) {
    uint v = 0;
#pragma unroll
    for (int b = 0; b < 4; ++b) {
      float f = src[q * 4 + b] * inv;
      int iq = (int)rintf(fminf(fmaxf(f, -127.f), 127.f));
      v |= ((uint)(unsigned char)(signed char)iq) << (8 * b);
    }
    pk[q] = v;
  }
  WF8[t] = (uint4){pk[0], pk[1], pk[2], pk[3]};
}

__global__ void k_bad(float* __restrict__ out, int n) {
  int i = blockIdx.x * blockDim.x + threadIdx.x;
  if (i < n) out[i] = 54321.f;
}

// ---------------- phase 1: fp16 MFMA GEMM (unchanged) ----------------

__device__ __forceinline__ void gload_lds16(const void* g, void* l) {
  __builtin_amdgcn_global_load_lds((const __attribute__((address_space(1))) void*)g,
                                   (__attribute__((address_space(3))) void*)l, 16, 0, 0);
}

__global__ __launch_bounds__(256) void k_gemm(const ushort* __restrict__ A,
                                              const ushort* __restrict__ W,
                                              const float* __restrict__ biasc,
                                              ushort* __restrict__ xp) {
  __shared__ __align__(16) ushort As[128 * 32];
  __shared__ __align__(16) ushort Bs[128 * 32];
  const int bid = blockIdx.x;
  const int m0 = (bid >> 4) * 128;
  const int n0 = (bid & 15) * 128;
  const int tid = threadIdx.x;
  const int wid = tid >> 6, lane = tid & 63;
  const int wr = wid >> 1, wcq = wid & 1;
  const int l16 = lane & 15, lq = lane >> 4;

  f32x4 acc[4][4] = {};

  for (int kt = 0; kt < KT; kt += 32) {
    __syncthreads();
#pragma unroll
    for (int i = 0; i < 2; ++i) {
      int ch = wid * 2 + i;
      int p = ch * 64 + lane;
      int r = p >> 2, gp = p & 3;
      int gs = gp ^ ((r >> 1) & 3);
      gload_lds16(A + (size_t)(m0 + r) * KT + kt + gs * 8, (char*)As + ch * 1024);
      gload_lds16(W + (size_t)(n0 + r) * KT + kt + gs * 8, (char*)Bs + ch * 1024);
    }
    __syncthreads();

    half8 af[4], bfr[4];
#pragma unroll
    for (int mfi = 0; mfi < 4; ++mfi) {
      int row = wr * 64 + mfi * 16 + l16;
      int g = lq ^ ((row >> 1) & 3);
      af[mfi] = *(const half8*)((const char*)As + row * 64 + g * 16);
    }
#pragma unroll
    for (int nf = 0; nf < 4; ++nf) {
      int row = wcq * 64 + nf * 16 + l16;
      int g = lq ^ ((row >> 1) & 3);
      bfr[nf] = *(const half8*)((const char*)Bs + row * 64 + g * 16);
    }
#pragma unroll
    for (int mfi = 0; mfi < 4; ++mfi)
#pragma unroll
      for (int nf = 0; nf < 4; ++nf)
        acc[mfi][nf] = __builtin_amdgcn_mfma_f32_16x16x32_f16(af[mfi], bfr[nf], acc[mfi][nf], 0, 0, 0);
  }

#pragma unroll
  for (int nf = 0; nf < 4; ++nf) {
    int col = n0 + wcq * 64 + nf * 16 + l16;
    float bv = biasc[col];
#pragma unroll
    for (int mfi = 0; mfi < 4; ++mfi) {
      int rbase = m0 + wr * 64 + mfi * 16 + lq * 4;
#pragma unroll
      for (int i = 0; i < 4; ++i)
        xp[(size_t)(rbase + i) * NC + col] = f2h(acc[mfi][nf][i] + bv);
    }
  }
}

// ---------------- phase 2: zero-comm i8 MFMA recurrence, pipelined step ----------------
// bid: dir = &1, bl = >>1. Wave w owns outputs 32w..32w+31 (tiles g*16+2w+j).
// Per step: B-frag reads -> xp(t+1) prefetch -> j0 MFMAs -> j0 bounce -> j1 MFMAs
// -> j1 bounce -> gates (regs only) -> act (rcp) -> h write -> barrier.

__global__ __launch_bounds__(512, 2) void k_lstm(const uint4* __restrict__ WF8,
                                                 const float* __restrict__ sq,
                                                 const ushort* __restrict__ xp,
                                                 float* __restrict__ out,
                                                 int b_base) {
  const int dir = blockIdx.x & 1;
  const int bl  = blockIdx.x >> 1;
  const int tid = threadIdx.x;
  const int w    = tid >> 6;
  const int lane = tid & 63;
  const int lq   = lane >> 4;
  const int n    = lane & 31;          // this lane's output (2x redundant)

  __shared__ __align__(16) char hq[2][256];    // i8 h, parity double-buffered
  __shared__ __align__(16) int  gbuf[8][128];  // i32 gate bounce, per-wave

  // ---- persistent weights: all 32 i8 frags in registers ----
  const uint4* wfb = WF8 + (size_t)((dir * 8 + w) * 32) * 64 + lane;
  uint4 wA[32];
#pragma unroll
  for (int f = 0; f < 32; ++f) wA[f] = wfb[(size_t)f * 64];

  // per-output dequant scales (4 gate rows), includes the 1/127 h-scale
  float fdq[4];
#pragma unroll
  for (int g = 0; g < 4; ++g)
    fdq[g] = sq[dir * 1024 + g * 256 + 32 * w + n] * (1.f / 127.f);

  if (tid < 128) ((uint*)hq)[tid] = 0;         // h_{-1} = 0 (both buffers)
  float creg = 0.f;
  __syncthreads();

  const int dstep = dir ? -1 : 1;
  const int t0 = dir ? (Tn - 1) : 0;
  const ptrdiff_t xstr = (ptrdiff_t)dstep * NC;
  const ptrdiff_t ostr = (ptrdiff_t)dstep * 512;
  const ushort* px = xp + (size_t)(bl * Tn + t0) * NC + dir * 1024 + 32 * w + n;
  float* pout = out + (size_t)((b_base + bl) * Tn + t0) * 512 + dir * 256 + 32 * w + n;

  // preload xp for t=0 (fp32)
  float xc0 = h2f(px[0]), xc1 = h2f(px[256]), xc2 = h2f(px[512]), xc3 = h2f(px[768]);

  int cur = 0;
#pragma unroll 1
  for (int t = 0; t < Tn; ++t) {
    // B-frags: 16 i8 h-values per kt (uniform per lane-quad)
    uint4 bq[4];
#pragma unroll
    for (int kt = 0; kt < 4; ++kt)
      bq[kt] = *(const uint4*)(hq[cur] + kt * 64 + lq * 16);

    // prefetch xp for t+1 (consumed at NEXT step's tail: ~2 phases of cover)
    float xn0 = 0.f, xn1 = 0.f, xn2 = 0.f, xn3 = 0.f;
    if (t + 1 < Tn) {
      px += xstr;
      xn0 = h2f(px[0]); xn1 = h2f(px[256]); xn2 = h2f(px[512]); xn3 = h2f(px[768]);
    }

    i32x4 acc[8];
#pragma unroll
    for (int m = 0; m < 8; ++m) acc[m] = (i32x4){0, 0, 0, 0};

    // j=0 chains (m = 0,2,4,6)
#pragma unroll
    for (int kt = 0; kt < 4; ++kt)
#pragma unroll
      for (int m = 0; m < 8; m += 2)
        acc[m] = mfi8(wA[kt * 8 + m], bq[kt], acc[m]);
    // j0 bounce early: write hides under j1 MFMAs (slots g*32 + 0 + lq*4)
    if ((lane & 15) == 0) {
#pragma unroll
      for (int m = 0; m < 8; m += 2)
        *(i32x4*)&gbuf[w][(m >> 1) * 32 + lq * 4] = acc[m];
    }
    // j=1 chains (m = 1,3,5,7)
#pragma unroll
    for (int kt = 0; kt < 4; ++kt)
#pragma unroll
      for (int m = 1; m < 8; m += 2)
        acc[m] = mfi8(wA[kt * 8 + m], bq[kt], acc[m]);
    if ((lane & 15) == 0) {
#pragma unroll
      for (int m = 1; m < 8; m += 2)
        *(i32x4*)&gbuf[w][(m >> 1) * 32 + 16 + lq * 4] = acc[m];
    }

    // gates for output n (slot = g*32 + n); same-wave LDS dep (compiler lgkmcnt)
    float gi = (float)gbuf[w][0 * 32 + n] * fdq[0] + xc0;
    float gf = (float)gbuf[w][1 * 32 + n] * fdq[1] + xc1;
    float gg = (float)gbuf[w][2 * 32 + n] * fdq[2] + xc2;
    float go = (float)gbuf[w][3 * 32 + n] * fdq[3] + xc3;
    float iv = sigr_(gi), fv = sigr_(gf), gv = tanhr_(gg), ov = sigr_(go);
    creg = fv * creg + iv * gv;
    float h = ov * tanhr_(creg);
    if (lane < 32) {
      *pout = h;                                   // fp32 output (drains lazily)
      int q = (int)rintf(h * 127.f);               // |h|<1 -> q in [-127,127]
      hq[cur ^ 1][32 * w + n] = (char)q;           // i8 h for next step
    }
    pout += ostr;
    xc0 = xn0; xc1 = xn1; xc2 = xn2; xc3 = xn3;
    barrier_lgkm();                                // h_t visible to all waves
    cur ^= 1;
  }
  (void)sig_;                                      // keep helper referenced-safe
}

// ---------------- host ----------------

extern "C" void kernel_launch(void* const* d_in, const int* in_sizes, int n_in,
                              void* d_out, int out_size, void* d_ws, size_t ws_size,
                              hipStream_t stream) {
  const float* x     = (const float*)d_in[0];
  const float* Wih_f = (const float*)d_in[1];
  const float* Whh_f = (const float*)d_in[2];
  const float* bih_f = (const float*)d_in[3];
  const float* bhh_f = (const float*)d_in[4];
  const float* Wih_b = (const float*)d_in[5];
  const float* Whh_b = (const float*)d_in[6];
  const float* bib_b = (const float*)d_in[7];
  const float* bhh_b = (const float*)d_in[8];
  float* out = (float*)d_out;

  const size_t szW16  = (size_t)NC * KT * 2;            // 2 MiB
  const size_t szBias = (size_t)NC * 4;
  const size_t szSq   = 2048 * 4;                       // 8 KiB row scales
  const size_t szWF8  = (size_t)2 * 8 * 32 * 64 * 16;   // 512 KiB i8 frag buffer

  int c = 0;
  size_t szA16 = 0, szXp = 0;
  for (int cc = 1; cc <= 16; cc *= 2) {
    size_t a = (size_t)(Bn / cc) * Tn * KT * 2;
    size_t p = (size_t)(Bn / cc) * Tn * NC * 2;
    if (szW16 + szBias + szSq + szWF8 + a + p <= ws_size) { c = cc; szA16 = a; szXp = p; break; }
  }
  if (c == 0) {
    k_bad<<<(out_size + 255) / 256, 256, 0, stream>>>(out, out_size);
    return;
  }

  char* ws = (char*)d_ws;
  ushort* W16   = (ushort*)ws;
  float*  biasc = (float*)(ws + szW16);
  float*  sq    = (float*)(ws + szW16 + szBias);
  uint4*  WF8   = (uint4*)(ws + szW16 + szBias + szSq);
  ushort* A16   = (ushort*)(ws + szW16 + szBias + szSq + szWF8);
  ushort* xp    = (ushort*)(ws + szW16 + szBias + szSq + szWF8 + szA16);

  {
    long n4 = (long)NC * (KT / 4);
    k_prep_w<<<(int)((n4 + 255) / 256), 256, 0, stream>>>(Wih_f, Wih_b, bih_f, bhh_f,
                                                          bib_b, bhh_b, W16, biasc);
  }
  k_scale<<<8, 256, 0, stream>>>(Whh_f, Whh_b, sq);
  k_prep_whh8<<<(2 * 8 * 32 * 64) / 256, 256, 0, stream>>>(Whh_f, Whh_b, sq, WF8);

  const int sizeB = Bn / c;
  for (int cb = 0; cb < c; ++cb) {
    const int b_base = cb * sizeB;
    {
      long nquad = (long)sizeB * Tn * KT / 4;
      k_prep_a<<<(int)((nquad + 255) / 256), 256, 0, stream>>>(
          x + (size_t)b_base * Tn * Dn, A16, nquad);
    }
    k_gemm<<<dim3(sizeB * 8 * 16), dim3(256), 0, stream>>>(A16, W16, biasc, xp);
    k_lstm<<<dim3(2 * sizeB), dim3(512), 0, stream>>>(WF8, sq, xp, out, b_base);
  }
}